// Round 3
// baseline (235.211 us; speedup 1.0000x reference)
//
#include <hip/hip_runtime.h>

typedef __bf16 v8bf __attribute__((ext_vector_type(8)));
typedef float  v4f  __attribute__((ext_vector_type(4)));
typedef float  v16f __attribute__((ext_vector_type(16)));
typedef unsigned short u16;

__device__ __forceinline__ u16 f2bf(float f){
  __bf16 h = (__bf16)f;
  union { __bf16 h; u16 u; } c; c.h = h; return c.u;
}
__device__ __forceinline__ v4f v4zero(){ v4f z; z[0]=0.f; z[1]=0.f; z[2]=0.f; z[3]=0.f; return z; }

#define MFMA16(a,b,c) __builtin_amdgcn_mfma_f32_16x16x32_bf16((a),(b),(c),0,0,0)
#define MFMA32(a,b,c) __builtin_amdgcn_mfma_f32_32x32x16_bf16((a),(b),(c),0,0,0)

// async global->LDS, 16B per lane; LDS dest = wave-uniform base + lane*16
__device__ __forceinline__ void gl_lds16(const u16* g, u16* l){
  __builtin_amdgcn_global_load_lds((const __attribute__((address_space(1))) void*)g,
                                   (__attribute__((address_space(3))) void*)l, 16, 0, 0);
}

// v_cvt_pk_bf16_f32: pack two f32 -> one u32 of 2 bf16 (no builtin on gfx950)
__device__ __forceinline__ unsigned int pkbf(float lo, float hi){
  unsigned int r;
  asm("v_cvt_pk_bf16_f32 %0, %1, %2" : "=v"(r) : "v"(lo), "v"(hi));
  return r;
}

// ============ f32 -> bf16 bulk convert, both weight tensors in one launch ============
__global__ __launch_bounds__(256) void cvt2_kernel(const float* __restrict__ a, u16* __restrict__ da, int na,
                                                   const float* __restrict__ b, u16* __restrict__ db, int nb){
  int i = (blockIdx.x*256 + threadIdx.x)*4;
  const float* s; u16* d; int off;
  if (i < na){ s = a; d = da; off = i; }
  else { off = i - na; if (off >= nb) return; s = b; d = db; }
  float4 v = *(const float4*)(s + off);
  ushort4 o;
  o.x = f2bf(v.x); o.y = f2bf(v.y); o.z = f2bf(v.z); o.w = f2bf(v.w);
  *(ushort4*)(d + off) = o;
}

// ============ Fused GroupNorm: stats + apply + transpose in one kernel ============
__global__ __launch_bounds__(256) void gn_fused_kernel(const float* __restrict__ x, const float* __restrict__ nw,
                                                       const float* __restrict__ nb, u16* __restrict__ h_t){
  __shared__ float xs[16*1028 + 16];
  const int bg = blockIdx.x, b = bg >> 5, g = bg & 31, c0 = g*16;
  const int tid = threadIdx.x;
  const float* base = x + (size_t)(b*512 + c0)*1024;

  float s = 0.f, ss = 0.f;
  #pragma unroll
  for (int it = 0; it < 16; ++it){
    float4 v = *(const float4*)(base + it*1024 + tid*4);
    s  += v.x + v.y + v.z + v.w;
    ss += v.x*v.x + v.y*v.y + v.z*v.z + v.w*v.w;
    *(float4*)(xs + it*1028 + tid*4) = v;
  }
  #pragma unroll
  for (int off = 32; off > 0; off >>= 1){ s += __shfl_down(s, off); ss += __shfl_down(ss, off); }
  float* red = xs + 16*1028;
  int w = tid >> 6;
  if ((tid & 63) == 0){ red[w] = s; red[4+w] = ss; }
  __syncthreads();
  if (tid == 0){
    float S  = red[0]+red[1]+red[2]+red[3];
    float SS = red[4]+red[5]+red[6]+red[7];
    float mean = S * (1.f/16384.f);
    float var  = SS * (1.f/16384.f) - mean*mean;
    red[8] = mean;
    red[9] = rsqrtf(var + 1e-5f);
  }
  __syncthreads();
  const float mean = red[8], rstd = red[9];

  const int half = tid & 1, nbase = tid >> 1;
  float wv[8], bv[8];
  #pragma unroll
  for (int cl = 0; cl < 8; ++cl){
    int c = c0 + half*8 + cl;
    wv[cl] = nw[c] * rstd;
    bv[cl] = nb[c] - mean * wv[cl];
  }
  #pragma unroll
  for (int p = 0; p < 8; ++p){
    int n = nbase + p*128;
    alignas(16) u16 tmp[8];
    #pragma unroll
    for (int cl = 0; cl < 8; ++cl)
      tmp[cl] = f2bf(xs[(half*8 + cl)*1028 + n] * wv[cl] + bv[cl]);
    *(int4*)(h_t + ((size_t)b*1024 + n)*512 + c0 + half*8) = *(int4*)tmp;
  }
}

// ============ Fused QKV GEMM, double-buffered BK=32, 1 barrier/iter ============
__global__ __launch_bounds__(256,2) void gemm_qkv_kernel(
    const u16* __restrict__ A,       // h_t  [16][1024][512]
    const u16* __restrict__ B,       // wq_bf [1536][512]
    const float* __restrict__ bias,  // qkv_b [1536] f32
    u16* __restrict__ qk_t, u16* __restrict__ v_ws)
{
  __shared__ u16 smem[24576];    // 49,152 B: 2 x (A 4096 + B 8192 u16)
  const int tid = threadIdx.x, w = tid>>6, lane = tid&63, col = lane&15, quad = lane>>4;
  const int m0 = blockIdx.y*128;       // n
  const int n0 = blockIdx.x*256;       // o
  const int b  = blockIdx.z;
  const int lr = lane>>2;
  const int gsw = ((lane&3) ^ (lr&3))*8;
  const u16* Ag = A + ((size_t)b*1024 + m0 + w*32 + lr)*512 + gsw;
  const u16* Bg = B + (size_t)(n0 + w*64 + lr)*512 + gsw;
  const int mw = (w&1)*64, nw = (w>>1)*128;
  const int fsw = (quad ^ (col&3))*8;

  v4f acc[4][8];
  #pragma unroll
  for (int i=0;i<4;++i)
    #pragma unroll
    for (int j=0;j<8;++j) acc[i][j] = v4zero();

  {
    u16* Ab = smem + (w*32)*32;
    u16* Bb = smem + 4096 + (w*64)*32;
    #pragma unroll
    for (int p = 0; p < 2; ++p) gl_lds16(Ag + (size_t)(p*16)*512, Ab + p*512);
    #pragma unroll
    for (int p = 0; p < 4; ++p) gl_lds16(Bg + (size_t)(p*16)*512, Bb + p*512);
  }

  for (int kt = 0; kt < 16; ++kt){
    __syncthreads();
    if (kt < 15){
      u16* Ab = smem + ((kt+1)&1)*12288 + (w*32)*32;
      u16* Bb = smem + ((kt+1)&1)*12288 + 4096 + (w*64)*32;
      int ko = (kt+1)*32;
      #pragma unroll
      for (int p = 0; p < 2; ++p) gl_lds16(Ag + (size_t)(p*16)*512 + ko, Ab + p*512);
      #pragma unroll
      for (int p = 0; p < 4; ++p) gl_lds16(Bg + (size_t)(p*16)*512 + ko, Bb + p*512);
    }
    const u16* As = smem + (kt&1)*12288;
    const u16* Bs = As + 4096;
    v8bf a[4], bb[8];
    #pragma unroll
    for (int i = 0; i < 4; ++i) a[i]  = *(const v8bf*)(As + (mw+i*16+col)*32 + fsw);
    #pragma unroll
    for (int j = 0; j < 8; ++j) bb[j] = *(const v8bf*)(Bs + (nw+j*16+col)*32 + fsw);
    #pragma unroll
    for (int i = 0; i < 4; ++i)
      #pragma unroll
      for (int j = 0; j < 8; ++j)
        acc[i][j] = MFMA16(a[i], bb[j], acc[i][j]);
  }
  __syncthreads();

  float bc[8];
  #pragma unroll
  for (int j = 0; j < 8; ++j)
    bc[j] = bias[n0 + nw + j*16 + col];

  if (n0 < 1024){
    u16* Cs = smem + w*(64*72);
    #pragma unroll
    for (int half = 0; half < 2; ++half){
      #pragma unroll
      for (int i = 0; i < 4; ++i)
        #pragma unroll
        for (int jj = 0; jj < 4; ++jj)
          #pragma unroll
          for (int r = 0; r < 4; ++r)
            Cs[(i*16+quad*4+r)*72 + jj*16+col] = f2bf(acc[i][half*4+jj][r] + bc[half*4+jj]);
      u16* dst = qk_t + (size_t)b*1024*1024;
      #pragma unroll
      for (int p = 0; p < 8; ++p){
        int rl = p*8 + (lane>>3), cl = (lane&7)*8;
        *(int4*)(dst + (size_t)(m0+mw+rl)*1024 + n0+nw+half*64+cl) = *(int4*)(Cs + rl*72 + cl);
      }
    }
  } else {
    u16* Ct = smem + w*(64*80);
    #pragma unroll
    for (int half = 0; half < 2; ++half){
      #pragma unroll
      for (int i = 0; i < 4; ++i)
        #pragma unroll
        for (int jj = 0; jj < 4; ++jj)
          #pragma unroll
          for (int r = 0; r < 4; ++r)
            Ct[(jj*16+col)*80 + i*16+quad*4+r] = f2bf(acc[i][half*4+jj][r] + bc[half*4+jj]);
      u16* dst = v_ws + (size_t)b*512*1024;
      #pragma unroll
      for (int p = 0; p < 8; ++p){
        int rl = p*8 + (lane>>3), cl = (lane&7)*8;
        *(int4*)(dst + (size_t)(n0-1024 + nw + half*64 + rl)*1024 + m0+mw+cl) = *(int4*)(Ct + rl*80 + cl);
      }
    }
  }
}

// ============ Generic bf16 GEMM (proj): dbuf BK=64, 1 barrier/iter ============
__global__ __launch_bounds__(256,2) void gemm_bt_kernel(
    const u16* __restrict__ A, long long sA,
    const u16* __restrict__ B, long long sB,
    u16* __restrict__ Cbf, float* __restrict__ Cf, long long sC,
    const float* __restrict__ bias_row,
    const float* __restrict__ bias_col,
    const float* __restrict__ residf, long long sR,
    int M, int N, int K)
{
  __shared__ u16 smem[32768];   // 65,536 B: 2 x (A 8192 + B 8192 u16)
  const int tid = threadIdx.x, w = tid>>6, lane = tid&63, col = lane&15, quad = lane>>4;
  const int m0 = blockIdx.y*128, n0 = blockIdx.x*128;
  const int lr8 = lane>>3;
  const int gsw = ((lane&7) ^ lr8)*8;
  const u16* Ag = A + (size_t)blockIdx.z*sA + (size_t)(m0 + w*32 + lr8)*K + gsw;
  const u16* Bg = B + (size_t)blockIdx.z*sB + (size_t)(n0 + w*32 + lr8)*K + gsw;
  const int mw = (w&1)*64, nw = (w>>1)*64;
  const int csw = col&7;
  const int nt = K >> 6;

  v4f acc[4][4];
  #pragma unroll
  for (int i=0;i<4;++i)
    #pragma unroll
    for (int j=0;j<4;++j) acc[i][j] = v4zero();

  {
    u16* Ab = smem + (w*32)*64;
    u16* Bb = smem + 8192 + (w*32)*64;
    #pragma unroll
    for (int p = 0; p < 4; ++p){
      gl_lds16(Ag + (size_t)(p*8)*K, Ab + p*512);
      gl_lds16(Bg + (size_t)(p*8)*K, Bb + p*512);
    }
  }

  for (int kt = 0; kt < nt; ++kt){
    __syncthreads();
    if (kt+1 < nt){
      u16* Ab = smem + ((kt+1)&1)*16384 + (w*32)*64;
      u16* Bb = smem + ((kt+1)&1)*16384 + 8192 + (w*32)*64;
      int ko = (kt+1)*64;
      #pragma unroll
      for (int p = 0; p < 4; ++p){
        gl_lds16(Ag + (size_t)(p*8)*K + ko, Ab + p*512);
        gl_lds16(Bg + (size_t)(p*8)*K + ko, Bb + p*512);
      }
    }
    const u16* As = smem + (kt&1)*16384;
    const u16* Bs = As + 8192;
    #pragma unroll
    for (int kh = 0; kh < 2; ++kh){
      const int fs = ((kh*4 + quad) ^ csw)*8;
      v8bf a[4], bb[4];
      #pragma unroll
      for (int i = 0; i < 4; ++i) a[i]  = *(const v8bf*)(As + (mw+i*16+col)*64 + fs);
      #pragma unroll
      for (int j = 0; j < 4; ++j) bb[j] = *(const v8bf*)(Bs + (nw+j*16+col)*64 + fs);
      #pragma unroll
      for (int i = 0; i < 4; ++i)
        #pragma unroll
        for (int j = 0; j < 4; ++j)
          acc[i][j] = MFMA16(a[i], bb[j], acc[i][j]);
    }
  }
  __syncthreads();

  float br[4][4], bc[4];
  #pragma unroll
  for (int i = 0; i < 4; ++i)
    #pragma unroll
    for (int r = 0; r < 4; ++r)
      br[i][r] = bias_row ? bias_row[m0+mw+i*16+quad*4+r] : 0.f;
  #pragma unroll
  for (int j = 0; j < 4; ++j)
    bc[j] = bias_col ? bias_col[n0+nw+j*16+col] : 0.f;

  if (Cf){
    float* Cb = Cf + (size_t)blockIdx.z*sC;
    const float* Rb = residf ? residf + (size_t)blockIdx.z*sR : nullptr;
    #pragma unroll
    for (int i = 0; i < 4; ++i)
      #pragma unroll
      for (int r = 0; r < 4; ++r){
        int row = m0+mw+i*16+quad*4+r;
        #pragma unroll
        for (int j = 0; j < 4; ++j){
          size_t goff = (size_t)row*N + n0+nw+j*16+col;
          float val = acc[i][j][r] + br[i][r] + bc[j];
          if (Rb) val += Rb[goff];
          Cb[goff] = val;
        }
      }
  } else {
    u16* Cs = smem + w*(64*72);
    #pragma unroll
    for (int i = 0; i < 4; ++i)
      #pragma unroll
      for (int j = 0; j < 4; ++j)
        #pragma unroll
        for (int r = 0; r < 4; ++r)
          Cs[(i*16+quad*4+r)*72 + j*16+col] = f2bf(acc[i][j][r] + br[i][r] + bc[j]);
    __syncthreads();
    u16* Cb = Cbf + (size_t)blockIdx.z*sC;
    #pragma unroll
    for (int p = 0; p < 8; ++p){
      int rl = p*8 + (lane>>3), cl = (lane&7)*8;
      size_t goff = (size_t)(m0+mw+rl)*N + n0+nw+cl;
      *(int4*)(Cb + goff) = *(int4*)(Cs + rl*72 + cl);
    }
  }
}

// ============ Fused flash attention: K direct from L2 to registers, V via LDS ============
// qk[b][n][0..511]=q, [512..1023]=k; vv[b][c_all][m]; out[b][n][c_all]
// flat grid 512 x 256: qt=id>>6, bh=id&63. 2 blocks/CU (32KB LDS each), 2 waves/SIMD.
// K fragments are contiguous 16B in global (row m, ch 512+h*128+granule) and the per-(b,h)
// K/V set (512KB) is L2-resident -> load K straight to VGPRs (VMEM pipe), halving the
// LDS-read pipe load (the measured floor) and halving the barrier's vmcnt drain volume.
// K regs for tile t+1 are reloaded right after QK(t) consumes them (last use) -> the
// ~300cy L2 latency flies over exp/pack/PV. V keeps the verified dbuf-LDS path.
// In-register softmax via swapped QK^T (T12: cvt_pk + permlane32_swap), no P buffer.
__global__ __launch_bounds__(256,2) void attn_kernel(const u16* __restrict__ qk, const u16* __restrict__ vv,
                                                     u16* __restrict__ outp){
  __shared__ u16 smem[16384];        // Vs dbuf 2 x [128][64] = 32KB; epilogue reuses as [128][128]
  u16* Vs = smem;
  const int id = blockIdx.x;
  const int qt = id >> 6, bh = id & 63, b = bh >> 2, h = bh & 3;
  const int n0 = qt*128;
  const int tid = threadIdx.x, w = tid>>6, lane = tid&63;
  const int nl = lane & 31, hi = lane >> 5;
  const int key = nl & 7;
  const size_t bq = (size_t)b*1024*1024;
  const float scale2 = 0.12751742f;  // (1/sqrt(128)) * log2(e)

  // Q as B-operand fragments in registers: col n = n0+w*32+nl, k granule kk*2+hi
  v8bf qf[8];
  {
    const u16* qbase = qk + bq + (size_t)(n0 + w*32 + nl)*1024 + h*128 + hi*8;
    #pragma unroll
    for (int kk = 0; kk < 8; ++kk)
      qf[kk] = *(const v8bf*)(qbase + kk*16);
  }

  // K A-operand fragments straight from global: row m = mt + g*32 + nl, ch 512+h*128+(kk*2+hi)*8
  const u16* kbase = qk + bq + (size_t)nl*1024 + 512 + h*128 + hi*8;

  v16f o[4];
  #pragma unroll
  for (int j=0;j<4;++j)
    #pragma unroll
    for (int r=0;r<16;++r) o[j][r] = 0.f;
  float lsum = 0.f;

  // V staging lane constants (swizzle folded into global source granule) — verified path
  const int vrow = w*8 + (lane>>3);
  const int vgr  = (lane&7) ^ (vrow&7);
  const u16* vg_base = vv + ((size_t)b*512 + h*128 + vrow)*1024 + vgr*8;

  // prologue: stage V(0) into buf 0; load K(0) fragments
  #pragma unroll
  for (int p = 0; p < 4; ++p)
    gl_lds16(vg_base + (size_t)(p*32)*1024, Vs + (w*8)*64 + p*2048);
  v8bf kX[8], kY[8];
  #pragma unroll
  for (int kk = 0; kk < 8; ++kk){
    kX[kk] = *(const v8bf*)(kbase + kk*16);
    kY[kk] = *(const v8bf*)(kbase + (size_t)32*1024 + kk*16);
  }

  for (int t = 0; t < 16; ++t){
    __syncthreads();                       // V(t) resident; K(t) regs drained by barrier's vmcnt(0)

    if (t < 15){                           // V prefetch t+1; flies over the whole compute phase
      int mt2 = t*64 + 64;
      u16* vl = Vs + (((t+1)&1)<<13) + (w*8)*64;
      #pragma unroll
      for (int p = 0; p < 4; ++p)
        gl_lds16(vg_base + (size_t)(p*32)*1024 + mt2, vl + p*2048);
    }

    // S^T = K Q^T (raw): s0 covers m = mt+0..31, s1 covers m = mt+32..63; col = q-row nl
    v16f s0, s1;
    #pragma unroll
    for (int r=0;r<16;++r){ s0[r]=0.f; s1[r]=0.f; }
    __builtin_amdgcn_s_setprio(1);
    #pragma unroll
    for (int kk = 0; kk < 8; ++kk){
      s0 = MFMA32(kX[kk], qf[kk], s0);
      s1 = MFMA32(kY[kk], qf[kk], s1);
    }
    __builtin_amdgcn_s_setprio(0);

    if (t < 15){                           // reload K for t+1; flies over exp/pack/PV
      const u16* kt = kbase + (size_t)(t*64 + 64)*1024;
      #pragma unroll
      for (int kk = 0; kk < 8; ++kk){
        kX[kk] = *(const v8bf*)(kt + kk*16);
        kY[kk] = *(const v8bf*)(kt + (size_t)32*1024 + kk*16);
      }
    }

    // p = exp2(s*scale2) in place; lane-local row-sum (all regs belong to q-row nl)
    #pragma unroll
    for (int r = 0; r < 16; ++r){
      s0[r] = __builtin_amdgcn_exp2f(s0[r]*scale2);
      s1[r] = __builtin_amdgcn_exp2f(s1[r]*scale2);
      lsum += s0[r] + s1[r];
    }

    // O += P V^T, P packed to A-frags in-register (cvt_pk + permlane32_swap)
    const u16* Vc = Vs + ((t&1)<<13);
    #pragma unroll
    for (int half = 0; half < 2; ++half){
      const v16f& ps = half ? s1 : s0;
      #pragma unroll
      for (int sel = 0; sel < 2; ++sel){
        const int sb = sel*8;
        unsigned int pA = pkbf(ps[sb+0], ps[sb+1]);
        unsigned int pB = pkbf(ps[sb+2], ps[sb+3]);
        unsigned int pC = pkbf(ps[sb+4], ps[sb+5]);
        unsigned int pD = pkbf(ps[sb+6], ps[sb+7]);
        asm("v_permlane32_swap_b32 %0, %1" : "+v"(pA), "+v"(pC));
        asm("v_permlane32_swap_b32 %0, %1" : "+v"(pB), "+v"(pD));
        union { v8bf v; unsigned int u[4]; } pa;
        pa.u[0] = pA; pa.u[1] = pB; pa.u[2] = pC; pa.u[3] = pD;
        const int kkv = half*2 + sel;
        const int gv = (((kkv*2 + hi) ^ key) << 3);
        __builtin_amdgcn_s_setprio(1);
        #pragma unroll
        for (int j = 0; j < 4; ++j){
          v8bf bv = *(const v8bf*)(Vc + ((j*32 + nl)<<6) + gv);
          o[j] = MFMA32(pa.v, bv, o[j]);
        }
        __builtin_amdgcn_s_setprio(0);
      }
    }
  }
  __syncthreads();

  // full row-sum for q-row nl (other half of m lives in lane^32), then redistribute
  // 1/l to the 32x32 C/D row layout: row(reg) = (reg&3) + 8*(reg>>2) + 4*hi
  lsum += __shfl_xor(lsum, 32);
  float invl[16];
  #pragma unroll
  for (int r = 0; r < 16; ++r){
    int nr = (r&3) + 8*(r>>2) + 4*hi;
    invl[r] = 1.f / __shfl(lsum, nr);
  }

  // bounce O through LDS (swizzled [128][128]) for coalesced 16B stores
  #pragma unroll
  for (int j = 0; j < 4; ++j)
    #pragma unroll
    for (int r = 0; r < 16; ++r){
      int rr = w*32 + (r&3) + 8*(r>>2) + 4*hi;
      int c  = j*32 + nl;
      smem[(rr<<7) + ((((c>>3) ^ (rr&7))<<3)) + (c&7)] = f2bf(o[j][r] * invl[r]);
    }
  __syncthreads();
  #pragma unroll
  for (int p = 0; p < 8; ++p){
    int nr = p*16 + (tid>>4);
    int gc = (tid&15) ^ (nr&7);
    *(int4*)(outp + ((size_t)b*1024 + n0 + nr)*512 + h*128 + ((tid&15)<<3)) =
      *(int4*)(smem + (nr<<7) + (gc<<3));
  }
}

extern "C" void kernel_launch(void* const* d_in, const int* in_sizes, int n_in,
                              void* d_out, int out_size, void* d_ws, size_t ws_size,
                              hipStream_t stream){
  const float* x      = (const float*)d_in[0];
  const float* norm_w = (const float*)d_in[1];
  const float* norm_b = (const float*)d_in[2];
  const float* qkv_w  = (const float*)d_in[3];
  const float* qkv_b  = (const float*)d_in[4];
  const float* proj_w = (const float*)d_in[5];
  const float* proj_b = (const float*)d_in[6];
  float* out = (float*)d_out;

  u16* h_t   = (u16*)d_ws;                                  // [16][1024][512]
  u16* qk_t  = h_t  + (size_t)16*1024*512;                  // [16][1024][1024]
  u16* v_ws  = qk_t + (size_t)16*1024*1024;                 // [16][512][1024]
  u16* wq_bf = v_ws + (size_t)16*512*1024;                  // [1536][512]
  u16* wp_bf = wq_bf + (size_t)1536*512;                    // [512][512]
  u16* attnout = h_t;                                       // reuse

  cvt2_kernel<<<1024, 256, 0, stream>>>(qkv_w, wq_bf, 1536*512, proj_w, wp_bf, 512*512);
  gn_fused_kernel<<<512, 256, 0, stream>>>(x, norm_w, norm_b, h_t);

  gemm_qkv_kernel<<<dim3(6,8,16), 256, 0, stream>>>(h_t, wq_bf, qkv_b, qk_t, v_ws);

  attn_kernel<<<512, 256, 0, stream>>>(qk_t, v_ws, attnout);

  gemm_bt_kernel<<<dim3(8,4,16), 256, 0, stream>>>(
      wp_bf, 0, attnout, (long long)1024*512,
      nullptr, out, (long long)512*1024, proj_b, nullptr, x, (long long)512*1024, 512, 1024, 512);
}

// Round 4
// 206.491 us; speedup vs baseline: 1.1391x; 1.1391x over previous
//
#include <hip/hip_runtime.h>

typedef __bf16 v8bf __attribute__((ext_vector_type(8)));
typedef float  v4f  __attribute__((ext_vector_type(4)));
typedef float  v16f __attribute__((ext_vector_type(16)));
typedef unsigned short u16;

__device__ __forceinline__ u16 f2bf(float f){
  __bf16 h = (__bf16)f;
  union { __bf16 h; u16 u; } c; c.h = h; return c.u;
}
__device__ __forceinline__ v4f v4zero(){ v4f z; z[0]=0.f; z[1]=0.f; z[2]=0.f; z[3]=0.f; return z; }

#define MFMA16(a,b,c) __builtin_amdgcn_mfma_f32_16x16x32_bf16((a),(b),(c),0,0,0)
#define MFMA32(a,b,c) __builtin_amdgcn_mfma_f32_32x32x16_bf16((a),(b),(c),0,0,0)

// async global->LDS, 16B per lane; LDS dest = wave-uniform base + lane*16
__device__ __forceinline__ void gl_lds16(const u16* g, u16* l){
  __builtin_amdgcn_global_load_lds((const __attribute__((address_space(1))) void*)g,
                                   (__attribute__((address_space(3))) void*)l, 16, 0, 0);
}

// v_cvt_pk_bf16_f32: pack two f32 -> one u32 of 2 bf16 (no builtin on gfx950)
__device__ __forceinline__ unsigned int pkbf(float lo, float hi){
  unsigned int r;
  asm("v_cvt_pk_bf16_f32 %0, %1, %2" : "=v"(r) : "v"(lo), "v"(hi));
  return r;
}

// ============ f32 -> bf16 bulk convert, both weight tensors in one launch ============
__global__ __launch_bounds__(256) void cvt2_kernel(const float* __restrict__ a, u16* __restrict__ da, int na,
                                                   const float* __restrict__ b, u16* __restrict__ db, int nb){
  int i = (blockIdx.x*256 + threadIdx.x)*4;
  const float* s; u16* d; int off;
  if (i < na){ s = a; d = da; off = i; }
  else { off = i - na; if (off >= nb) return; s = b; d = db; }
  float4 v = *(const float4*)(s + off);
  ushort4 o;
  o.x = f2bf(v.x); o.y = f2bf(v.y); o.z = f2bf(v.z); o.w = f2bf(v.w);
  *(ushort4*)(d + off) = o;
}

// ============ Fused GroupNorm: stats + apply + transpose in one kernel ============
__global__ __launch_bounds__(256) void gn_fused_kernel(const float* __restrict__ x, const float* __restrict__ nw,
                                                       const float* __restrict__ nb, u16* __restrict__ h_t){
  __shared__ float xs[16*1028 + 16];
  const int bg = blockIdx.x, b = bg >> 5, g = bg & 31, c0 = g*16;
  const int tid = threadIdx.x;
  const float* base = x + (size_t)(b*512 + c0)*1024;

  float s = 0.f, ss = 0.f;
  #pragma unroll
  for (int it = 0; it < 16; ++it){
    float4 v = *(const float4*)(base + it*1024 + tid*4);
    s  += v.x + v.y + v.z + v.w;
    ss += v.x*v.x + v.y*v.y + v.z*v.z + v.w*v.w;
    *(float4*)(xs + it*1028 + tid*4) = v;
  }
  #pragma unroll
  for (int off = 32; off > 0; off >>= 1){ s += __shfl_down(s, off); ss += __shfl_down(ss, off); }
  float* red = xs + 16*1028;
  int w = tid >> 6;
  if ((tid & 63) == 0){ red[w] = s; red[4+w] = ss; }
  __syncthreads();
  if (tid == 0){
    float S  = red[0]+red[1]+red[2]+red[3];
    float SS = red[4]+red[5]+red[6]+red[7];
    float mean = S * (1.f/16384.f);
    float var  = SS * (1.f/16384.f) - mean*mean;
    red[8] = mean;
    red[9] = rsqrtf(var + 1e-5f);
  }
  __syncthreads();
  const float mean = red[8], rstd = red[9];

  const int half = tid & 1, nbase = tid >> 1;
  float wv[8], bv[8];
  #pragma unroll
  for (int cl = 0; cl < 8; ++cl){
    int c = c0 + half*8 + cl;
    wv[cl] = nw[c] * rstd;
    bv[cl] = nb[c] - mean * wv[cl];
  }
  #pragma unroll
  for (int p = 0; p < 8; ++p){
    int n = nbase + p*128;
    alignas(16) u16 tmp[8];
    #pragma unroll
    for (int cl = 0; cl < 8; ++cl)
      tmp[cl] = f2bf(xs[(half*8 + cl)*1028 + n] * wv[cl] + bv[cl]);
    *(int4*)(h_t + ((size_t)b*1024 + n)*512 + c0 + half*8) = *(int4*)tmp;
  }
}

// ============ Fused QKV GEMM, double-buffered BK=32, 1 barrier/iter ============
__global__ __launch_bounds__(256,2) void gemm_qkv_kernel(
    const u16* __restrict__ A,       // h_t  [16][1024][512]
    const u16* __restrict__ B,       // wq_bf [1536][512]
    const float* __restrict__ bias,  // qkv_b [1536] f32
    u16* __restrict__ qk_t, u16* __restrict__ v_ws)
{
  __shared__ u16 smem[24576];    // 49,152 B: 2 x (A 4096 + B 8192 u16)
  const int tid = threadIdx.x, w = tid>>6, lane = tid&63, col = lane&15, quad = lane>>4;
  const int m0 = blockIdx.y*128;       // n
  const int n0 = blockIdx.x*256;       // o
  const int b  = blockIdx.z;
  const int lr = lane>>2;
  const int gsw = ((lane&3) ^ (lr&3))*8;
  const u16* Ag = A + ((size_t)b*1024 + m0 + w*32 + lr)*512 + gsw;
  const u16* Bg = B + (size_t)(n0 + w*64 + lr)*512 + gsw;
  const int mw = (w&1)*64, nw = (w>>1)*128;
  const int fsw = (quad ^ (col&3))*8;

  v4f acc[4][8];
  #pragma unroll
  for (int i=0;i<4;++i)
    #pragma unroll
    for (int j=0;j<8;++j) acc[i][j] = v4zero();

  {
    u16* Ab = smem + (w*32)*32;
    u16* Bb = smem + 4096 + (w*64)*32;
    #pragma unroll
    for (int p = 0; p < 2; ++p) gl_lds16(Ag + (size_t)(p*16)*512, Ab + p*512);
    #pragma unroll
    for (int p = 0; p < 4; ++p) gl_lds16(Bg + (size_t)(p*16)*512, Bb + p*512);
  }

  for (int kt = 0; kt < 16; ++kt){
    __syncthreads();
    if (kt < 15){
      u16* Ab = smem + ((kt+1)&1)*12288 + (w*32)*32;
      u16* Bb = smem + ((kt+1)&1)*12288 + 4096 + (w*64)*32;
      int ko = (kt+1)*32;
      #pragma unroll
      for (int p = 0; p < 2; ++p) gl_lds16(Ag + (size_t)(p*16)*512 + ko, Ab + p*512);
      #pragma unroll
      for (int p = 0; p < 4; ++p) gl_lds16(Bg + (size_t)(p*16)*512 + ko, Bb + p*512);
    }
    const u16* As = smem + (kt&1)*12288;
    const u16* Bs = As + 4096;
    v8bf a[4], bb[8];
    #pragma unroll
    for (int i = 0; i < 4; ++i) a[i]  = *(const v8bf*)(As + (mw+i*16+col)*32 + fsw);
    #pragma unroll
    for (int j = 0; j < 8; ++j) bb[j] = *(const v8bf*)(Bs + (nw+j*16+col)*32 + fsw);
    #pragma unroll
    for (int i = 0; i < 4; ++i)
      #pragma unroll
      for (int j = 0; j < 8; ++j)
        acc[i][j] = MFMA16(a[i], bb[j], acc[i][j]);
  }
  __syncthreads();

  float bc[8];
  #pragma unroll
  for (int j = 0; j < 8; ++j)
    bc[j] = bias[n0 + nw + j*16 + col];

  if (n0 < 1024){
    u16* Cs = smem + w*(64*72);
    #pragma unroll
    for (int half = 0; half < 2; ++half){
      #pragma unroll
      for (int i = 0; i < 4; ++i)
        #pragma unroll
        for (int jj = 0; jj < 4; ++jj)
          #pragma unroll
          for (int r = 0; r < 4; ++r)
            Cs[(i*16+quad*4+r)*72 + jj*16+col] = f2bf(acc[i][half*4+jj][r] + bc[half*4+jj]);
      u16* dst = qk_t + (size_t)b*1024*1024;
      #pragma unroll
      for (int p = 0; p < 8; ++p){
        int rl = p*8 + (lane>>3), cl = (lane&7)*8;
        *(int4*)(dst + (size_t)(m0+mw+rl)*1024 + n0+nw+half*64+cl) = *(int4*)(Cs + rl*72 + cl);
      }
    }
  } else {
    u16* Ct = smem + w*(64*80);
    #pragma unroll
    for (int half = 0; half < 2; ++half){
      #pragma unroll
      for (int i = 0; i < 4; ++i)
        #pragma unroll
        for (int jj = 0; jj < 4; ++jj)
          #pragma unroll
          for (int r = 0; r < 4; ++r)
            Ct[(jj*16+col)*80 + i*16+quad*4+r] = f2bf(acc[i][half*4+jj][r] + bc[half*4+jj]);
      u16* dst = v_ws + (size_t)b*512*1024;
      #pragma unroll
      for (int p = 0; p < 8; ++p){
        int rl = p*8 + (lane>>3), cl = (lane&7)*8;
        *(int4*)(dst + (size_t)(n0-1024 + nw + half*64 + rl)*1024 + m0+mw+cl) = *(int4*)(Ct + rl*80 + cl);
      }
    }
  }
}

// ============ Generic bf16 GEMM (proj): dbuf BK=64, 1 barrier/iter ============
__global__ __launch_bounds__(256,2) void gemm_bt_kernel(
    const u16* __restrict__ A, long long sA,
    const u16* __restrict__ B, long long sB,
    u16* __restrict__ Cbf, float* __restrict__ Cf, long long sC,
    const float* __restrict__ bias_row,
    const float* __restrict__ bias_col,
    const float* __restrict__ residf, long long sR,
    int M, int N, int K)
{
  __shared__ u16 smem[32768];   // 65,536 B: 2 x (A 8192 + B 8192 u16)
  const int tid = threadIdx.x, w = tid>>6, lane = tid&63, col = lane&15, quad = lane>>4;
  const int m0 = blockIdx.y*128, n0 = blockIdx.x*128;
  const int lr8 = lane>>3;
  const int gsw = ((lane&7) ^ lr8)*8;
  const u16* Ag = A + (size_t)blockIdx.z*sA + (size_t)(m0 + w*32 + lr8)*K + gsw;
  const u16* Bg = B + (size_t)blockIdx.z*sB + (size_t)(n0 + w*32 + lr8)*K + gsw;
  const int mw = (w&1)*64, nw = (w>>1)*64;
  const int csw = col&7;
  const int nt = K >> 6;

  v4f acc[4][4];
  #pragma unroll
  for (int i=0;i<4;++i)
    #pragma unroll
    for (int j=0;j<4;++j) acc[i][j] = v4zero();

  {
    u16* Ab = smem + (w*32)*64;
    u16* Bb = smem + 8192 + (w*32)*64;
    #pragma unroll
    for (int p = 0; p < 4; ++p){
      gl_lds16(Ag + (size_t)(p*8)*K, Ab + p*512);
      gl_lds16(Bg + (size_t)(p*8)*K, Bb + p*512);
    }
  }

  for (int kt = 0; kt < nt; ++kt){
    __syncthreads();
    if (kt+1 < nt){
      u16* Ab = smem + ((kt+1)&1)*16384 + (w*32)*64;
      u16* Bb = smem + ((kt+1)&1)*16384 + 8192 + (w*32)*64;
      int ko = (kt+1)*64;
      #pragma unroll
      for (int p = 0; p < 4; ++p){
        gl_lds16(Ag + (size_t)(p*8)*K + ko, Ab + p*512);
        gl_lds16(Bg + (size_t)(p*8)*K + ko, Bb + p*512);
      }
    }
    const u16* As = smem + (kt&1)*16384;
    const u16* Bs = As + 8192;
    #pragma unroll
    for (int kh = 0; kh < 2; ++kh){
      const int fs = ((kh*4 + quad) ^ csw)*8;
      v8bf a[4], bb[4];
      #pragma unroll
      for (int i = 0; i < 4; ++i) a[i]  = *(const v8bf*)(As + (mw+i*16+col)*64 + fs);
      #pragma unroll
      for (int j = 0; j < 4; ++j) bb[j] = *(const v8bf*)(Bs + (nw+j*16+col)*64 + fs);
      #pragma unroll
      for (int i = 0; i < 4; ++i)
        #pragma unroll
        for (int j = 0; j < 4; ++j)
          acc[i][j] = MFMA16(a[i], bb[j], acc[i][j]);
    }
  }
  __syncthreads();

  float br[4][4], bc[4];
  #pragma unroll
  for (int i = 0; i < 4; ++i)
    #pragma unroll
    for (int r = 0; r < 4; ++r)
      br[i][r] = bias_row ? bias_row[m0+mw+i*16+quad*4+r] : 0.f;
  #pragma unroll
  for (int j = 0; j < 4; ++j)
    bc[j] = bias_col ? bias_col[n0+nw+j*16+col] : 0.f;

  if (Cf){
    float* Cb = Cf + (size_t)blockIdx.z*sC;
    const float* Rb = residf ? residf + (size_t)blockIdx.z*sR : nullptr;
    #pragma unroll
    for (int i = 0; i < 4; ++i)
      #pragma unroll
      for (int r = 0; r < 4; ++r){
        int row = m0+mw+i*16+quad*4+r;
        #pragma unroll
        for (int j = 0; j < 4; ++j){
          size_t goff = (size_t)row*N + n0+nw+j*16+col;
          float val = acc[i][j][r] + br[i][r] + bc[j];
          if (Rb) val += Rb[goff];
          Cb[goff] = val;
        }
      }
  } else {
    u16* Cs = smem + w*(64*72);
    #pragma unroll
    for (int i = 0; i < 4; ++i)
      #pragma unroll
      for (int j = 0; j < 4; ++j)
        #pragma unroll
        for (int r = 0; r < 4; ++r)
          Cs[(i*16+quad*4+r)*72 + j*16+col] = f2bf(acc[i][j][r] + br[i][r] + bc[j]);
    __syncthreads();
    u16* Cb = Cbf + (size_t)blockIdx.z*sC;
    #pragma unroll
    for (int p = 0; p < 8; ++p){
      int rl = p*8 + (lane>>3), cl = (lane&7)*8;
      size_t goff = (size_t)(m0+mw+rl)*N + n0+nw+cl;
      *(int4*)(Cb + goff) = *(int4*)(Cs + rl*72 + cl);
    }
  }
}

// ============ Fused flash attention: single-buffered K, dbuf V, 48KB LDS -> 3 blocks/CU ============
// qk[b][n][0..511]=q, [512..1023]=k; vv[b][c_all][m]; out[b][n][c_all]
// flat grid 512 x 256: qt=id>>6, bh=id&63. 3 blocks/CU (48KB LDS each), 12 waves/CU.
// Round-1 structure (46.6us) was pipe-serialized: LDS ~44% + MFMA ~29% + VALU ~30% ~= 100%
// with only 2 independent blocks/CU. K is fully consumed in the QK phase, so it needs no
// double buffer: B1 -> V-pf(t+1) -> QK(t) -> B2 -> K-pf(t+1) -> exp/pack -> PV(t).
// Each prefetch's vmcnt drain is covered by a compute phase; 3 drifting blocks/CU fill
// each other's serialization gaps. In-register softmax (T12) unchanged.
__global__ __launch_bounds__(256,2) void attn_kernel(const u16* __restrict__ qk, const u16* __restrict__ vv,
                                                     u16* __restrict__ outp){
  __shared__ u16 smem[24576];        // 48KB: Ks [64][128] (16KB) + Vs 2x[128][64] (32KB)
  u16* Ks = smem;                    // single buffer
  u16* Vs = smem + 8192;             // double buffer
  const int id = blockIdx.x;
  const int qt = id >> 6, bh = id & 63, b = bh >> 2, h = bh & 3;
  const int n0 = qt*128;
  const int tid = threadIdx.x, w = tid>>6, lane = tid&63;
  const int nl = lane & 31, hi = lane >> 5;
  const int key = nl & 7;
  const size_t bq = (size_t)b*1024*1024;
  const float scale2 = 0.12751742f;  // (1/sqrt(128)) * log2(e)

  // Q as B-operand fragments in registers: col n = n0+w*32+nl, k granule kk*2+hi
  v8bf qf[8];
  {
    const u16* qbase = qk + bq + (size_t)(n0 + w*32 + nl)*1024 + h*128 + hi*8;
    #pragma unroll
    for (int kk = 0; kk < 8; ++kk)
      qf[kk] = *(const v8bf*)(qbase + kk*16);
  }

  v16f o[4];
  #pragma unroll
  for (int j=0;j<4;++j)
    #pragma unroll
    for (int r=0;r<16;++r) o[j][r] = 0.f;
  float lsum = 0.f;

  // staging lane constants (swizzle folded into global source granule)
  const int krow = w*4 + (lane>>4);
  const int kgr  = (lane&15) ^ (krow&7);
  const u16* kg_base = qk + bq + (size_t)krow*1024 + 512 + h*128 + kgr*8;
  const int vrow = w*8 + (lane>>3);
  const int vgr  = (lane&7) ^ (vrow&7);
  const u16* vg_base = vv + ((size_t)b*512 + h*128 + vrow)*1024 + vgr*8;

  // prologue: stage K(0) and V(0)
  #pragma unroll
  for (int p = 0; p < 4; ++p)
    gl_lds16(kg_base + (size_t)(p*16)*1024, Ks + (w*4)*128 + p*2048);
  #pragma unroll
  for (int p = 0; p < 4; ++p)
    gl_lds16(vg_base + (size_t)(p*32)*1024, Vs + (w*8)*64 + p*2048);

  for (int t = 0; t < 16; ++t){
    const int mt = t*64;
    __syncthreads();                       // B1: K(t) and V(t) resident

    if (t < 15){                           // V prefetch t+1 -> other buffer; drains at B2 (covered by QK)
      int mt2 = mt + 64;
      u16* vl = Vs + (((t+1)&1)<<13) + (w*8)*64;
      #pragma unroll
      for (int p = 0; p < 4; ++p)
        gl_lds16(vg_base + (size_t)(p*32)*1024 + mt2, vl + p*2048);
    }

    // S^T = K Q^T (raw): s0 covers m = mt+0..31, s1 covers m = mt+32..63; col = q-row nl
    v16f s0, s1;
    #pragma unroll
    for (int r=0;r<16;++r){ s0[r]=0.f; s1[r]=0.f; }
    __builtin_amdgcn_s_setprio(1);
    #pragma unroll
    for (int kk = 0; kk < 8; ++kk){
      int g = (((kk*2 + hi) ^ key) << 3);
      v8bf k0 = *(const v8bf*)(Ks + (nl<<7) + g);
      v8bf k1 = *(const v8bf*)(Ks + ((32+nl)<<7) + g);
      s0 = MFMA32(k0, qf[kk], s0);
      s1 = MFMA32(k1, qf[kk], s1);
    }
    __builtin_amdgcn_s_setprio(0);

    __syncthreads();                       // B2: all waves consumed K(t); Ks free

    if (t < 15){                           // K prefetch t+1 -> Ks; drains at B1' (covered by exp+PV)
      int mt2 = mt + 64;
      #pragma unroll
      for (int p = 0; p < 4; ++p)
        gl_lds16(kg_base + (size_t)(mt2 + p*16)*1024, Ks + (w*4)*128 + p*2048);
    }

    // p = exp2(s*scale2) in place; lane-local row-sum (all regs belong to q-row nl)
    #pragma unroll
    for (int r = 0; r < 16; ++r){
      s0[r] = __builtin_amdgcn_exp2f(s0[r]*scale2);
      s1[r] = __builtin_amdgcn_exp2f(s1[r]*scale2);
      lsum += s0[r] + s1[r];
    }

    // O += P V^T, P packed to A-frags in-register (cvt_pk + permlane32_swap)
    const u16* Vc = Vs + ((t&1)<<13);
    #pragma unroll
    for (int half = 0; half < 2; ++half){
      const v16f& ps = half ? s1 : s0;
      #pragma unroll
      for (int sel = 0; sel < 2; ++sel){
        const int sb = sel*8;
        unsigned int pA = pkbf(ps[sb+0], ps[sb+1]);
        unsigned int pB = pkbf(ps[sb+2], ps[sb+3]);
        unsigned int pC = pkbf(ps[sb+4], ps[sb+5]);
        unsigned int pD = pkbf(ps[sb+6], ps[sb+7]);
        asm("v_permlane32_swap_b32 %0, %1" : "+v"(pA), "+v"(pC));
        asm("v_permlane32_swap_b32 %0, %1" : "+v"(pB), "+v"(pD));
        union { v8bf v; unsigned int u[4]; } pa;
        pa.u[0] = pA; pa.u[1] = pB; pa.u[2] = pC; pa.u[3] = pD;
        const int kkv = half*2 + sel;
        const int gv = (((kkv*2 + hi) ^ key) << 3);
        __builtin_amdgcn_s_setprio(1);
        #pragma unroll
        for (int j = 0; j < 4; ++j){
          v8bf bv = *(const v8bf*)(Vc + ((j*32 + nl)<<6) + gv);
          o[j] = MFMA32(pa.v, bv, o[j]);
        }
        __builtin_amdgcn_s_setprio(0);
      }
    }
  }
  __syncthreads();

  // full row-sum for q-row nl (other half of m lives in lane^32), then redistribute
  // 1/l to the 32x32 C/D row layout: row(reg) = (reg&3) + 8*(reg>>2) + 4*hi
  lsum += __shfl_xor(lsum, 32);
  float invl[16];
  #pragma unroll
  for (int r = 0; r < 16; ++r){
    int nr = (r&3) + 8*(r>>2) + 4*hi;
    invl[r] = 1.f / __shfl(lsum, nr);
  }

  // bounce O through LDS (swizzled [128][128]) for coalesced 16B stores
  #pragma unroll
  for (int j = 0; j < 4; ++j)
    #pragma unroll
    for (int r = 0; r < 16; ++r){
      int rr = w*32 + (r&3) + 8*(r>>2) + 4*hi;
      int c  = j*32 + nl;
      smem[(rr<<7) + ((((c>>3) ^ (rr&7))<<3)) + (c&7)] = f2bf(o[j][r] * invl[r]);
    }
  __syncthreads();
  #pragma unroll
  for (int p = 0; p < 8; ++p){
    int nr = p*16 + (tid>>4);
    int gc = (tid&15) ^ (nr&7);
    *(int4*)(outp + ((size_t)b*1024 + n0 + nr)*512 + h*128 + ((tid&15)<<3)) =
      *(int4*)(smem + (nr<<7) + (gc<<3));
  }
}

extern "C" void kernel_launch(void* const* d_in, const int* in_sizes, int n_in,
                              void* d_out, int out_size, void* d_ws, size_t ws_size,
                              hipStream_t stream){
  const float* x      = (const float*)d_in[0];
  const float* norm_w = (const float*)d_in[1];
  const float* norm_b = (const float*)d_in[2];
  const float* qkv_w  = (const float*)d_in[3];
  const float* qkv_b  = (const float*)d_in[4];
  const float* proj_w = (const float*)d_in[5];
  const float* proj_b = (const float*)d_in[6];
  float* out = (float*)d_out;

  u16* h_t   = (u16*)d_ws;                                  // [16][1024][512]
  u16* qk_t  = h_t  + (size_t)16*1024*512;                  // [16][1024][1024]
  u16* v_ws  = qk_t + (size_t)16*1024*1024;                 // [16][512][1024]
  u16* wq_bf = v_ws + (size_t)16*512*1024;                  // [1536][512]
  u16* wp_bf = wq_bf + (size_t)1536*512;                    // [512][512]
  u16* attnout = h_t;                                       // reuse

  cvt2_kernel<<<1024, 256, 0, stream>>>(qkv_w, wq_bf, 1536*512, proj_w, wp_bf, 512*512);
  gn_fused_kernel<<<512, 256, 0, stream>>>(x, norm_w, norm_b, h_t);

  gemm_qkv_kernel<<<dim3(6,8,16), 256, 0, stream>>>(h_t, wq_bf, qkv_b, qk_t, v_ws);

  attn_kernel<<<512, 256, 0, stream>>>(qk_t, v_ws, attnout);

  gemm_bt_kernel<<<dim3(8,4,16), 256, 0, stream>>>(
      wp_bf, 0, attnout, (long long)1024*512,
      nullptr, out, (long long)512*1024, proj_b, nullptr, x, (long long)512*1024, 512, 1024, 512);
}

// Round 5
// 203.091 us; speedup vs baseline: 1.1582x; 1.0167x over previous
//
#include <hip/hip_runtime.h>

typedef __bf16 v8bf __attribute__((ext_vector_type(8)));
typedef float  v4f  __attribute__((ext_vector_type(4)));
typedef float  v16f __attribute__((ext_vector_type(16)));
typedef unsigned short u16;

__device__ __forceinline__ u16 f2bf(float f){
  __bf16 h = (__bf16)f;
  union { __bf16 h; u16 u; } c; c.h = h; return c.u;
}
__device__ __forceinline__ v4f v4zero(){ v4f z; z[0]=0.f; z[1]=0.f; z[2]=0.f; z[3]=0.f; return z; }

#define MFMA16(a,b,c) __builtin_amdgcn_mfma_f32_16x16x32_bf16((a),(b),(c),0,0,0)
#define MFMA32(a,b,c) __builtin_amdgcn_mfma_f32_32x32x16_bf16((a),(b),(c),0,0,0)

// async global->LDS, 16B per lane; LDS dest = wave-uniform base + lane*16
__device__ __forceinline__ void gl_lds16(const u16* g, u16* l){
  __builtin_amdgcn_global_load_lds((const __attribute__((address_space(1))) void*)g,
                                   (__attribute__((address_space(3))) void*)l, 16, 0, 0);
}

// v_cvt_pk_bf16_f32: pack two f32 -> one u32 of 2 bf16 (no builtin on gfx950)
__device__ __forceinline__ unsigned int pkbf(float lo, float hi){
  unsigned int r;
  asm("v_cvt_pk_bf16_f32 %0, %1, %2" : "=v"(r) : "v"(lo), "v"(hi));
  return r;
}

// pack 8 f32 (P values) -> v8bf A-fragment via cvt_pk + permlane32_swap (T12)
#define PACK8(ps, base, dst) { \
  unsigned int pA = pkbf((ps)[(base)+0], (ps)[(base)+1]); \
  unsigned int pB = pkbf((ps)[(base)+2], (ps)[(base)+3]); \
  unsigned int pC = pkbf((ps)[(base)+4], (ps)[(base)+5]); \
  unsigned int pD = pkbf((ps)[(base)+6], (ps)[(base)+7]); \
  asm("v_permlane32_swap_b32 %0, %1" : "+v"(pA), "+v"(pC)); \
  asm("v_permlane32_swap_b32 %0, %1" : "+v"(pB), "+v"(pD)); \
  union { v8bf v; unsigned int u[4]; } pu; \
  pu.u[0]=pA; pu.u[1]=pB; pu.u[2]=pC; pu.u[3]=pD; \
  (dst) = pu.v; }

// one PV sub-block: 4 MFMA32 into o[0..3] using carried packed-P fragment
#define PVBLK(kkv, pa) { \
  const int gv_ = ((((kkv)*2 + hi) ^ key) << 3); \
  _Pragma("unroll") \
  for (int j_ = 0; j_ < 4; ++j_){ \
    v8bf bv_ = *(const v8bf*)(Vprev + ((j_*32 + nl)<<6) + gv_); \
    o[j_] = MFMA32((pa), bv_, o[j_]); } }

// ============ f32 -> bf16 bulk convert, both weight tensors in one launch ============
__global__ __launch_bounds__(256) void cvt2_kernel(const float* __restrict__ a, u16* __restrict__ da, int na,
                                                   const float* __restrict__ b, u16* __restrict__ db, int nb){
  int i = (blockIdx.x*256 + threadIdx.x)*4;
  const float* s; u16* d; int off;
  if (i < na){ s = a; d = da; off = i; }
  else { off = i - na; if (off >= nb) return; s = b; d = db; }
  float4 v = *(const float4*)(s + off);
  ushort4 o;
  o.x = f2bf(v.x); o.y = f2bf(v.y); o.z = f2bf(v.z); o.w = f2bf(v.w);
  *(ushort4*)(d + off) = o;
}

// ============ Fused GroupNorm: stats + apply + transpose in one kernel ============
__global__ __launch_bounds__(256) void gn_fused_kernel(const float* __restrict__ x, const float* __restrict__ nw,
                                                       const float* __restrict__ nb, u16* __restrict__ h_t){
  __shared__ float xs[16*1028 + 16];
  const int bg = blockIdx.x, b = bg >> 5, g = bg & 31, c0 = g*16;
  const int tid = threadIdx.x;
  const float* base = x + (size_t)(b*512 + c0)*1024;

  float s = 0.f, ss = 0.f;
  #pragma unroll
  for (int it = 0; it < 16; ++it){
    float4 v = *(const float4*)(base + it*1024 + tid*4);
    s  += v.x + v.y + v.z + v.w;
    ss += v.x*v.x + v.y*v.y + v.z*v.z + v.w*v.w;
    *(float4*)(xs + it*1028 + tid*4) = v;
  }
  #pragma unroll
  for (int off = 32; off > 0; off >>= 1){ s += __shfl_down(s, off); ss += __shfl_down(ss, off); }
  float* red = xs + 16*1028;
  int w = tid >> 6;
  if ((tid & 63) == 0){ red[w] = s; red[4+w] = ss; }
  __syncthreads();
  if (tid == 0){
    float S  = red[0]+red[1]+red[2]+red[3];
    float SS = red[4]+red[5]+red[6]+red[7];
    float mean = S * (1.f/16384.f);
    float var  = SS * (1.f/16384.f) - mean*mean;
    red[8] = mean;
    red[9] = rsqrtf(var + 1e-5f);
  }
  __syncthreads();
  const float mean = red[8], rstd = red[9];

  const int half = tid & 1, nbase = tid >> 1;
  float wv[8], bv[8];
  #pragma unroll
  for (int cl = 0; cl < 8; ++cl){
    int c = c0 + half*8 + cl;
    wv[cl] = nw[c] * rstd;
    bv[cl] = nb[c] - mean * wv[cl];
  }
  #pragma unroll
  for (int p = 0; p < 8; ++p){
    int n = nbase + p*128;
    alignas(16) u16 tmp[8];
    #pragma unroll
    for (int cl = 0; cl < 8; ++cl)
      tmp[cl] = f2bf(xs[(half*8 + cl)*1028 + n] * wv[cl] + bv[cl]);
    *(int4*)(h_t + ((size_t)b*1024 + n)*512 + c0 + half*8) = *(int4*)tmp;
  }
}

// ============ Fused QKV GEMM, double-buffered BK=32, 1 barrier/iter ============
__global__ __launch_bounds__(256,2) void gemm_qkv_kernel(
    const u16* __restrict__ A,       // h_t  [16][1024][512]
    const u16* __restrict__ B,       // wq_bf [1536][512]
    const float* __restrict__ bias,  // qkv_b [1536] f32
    u16* __restrict__ qk_t, u16* __restrict__ v_ws)
{
  __shared__ u16 smem[24576];    // 49,152 B: 2 x (A 4096 + B 8192 u16)
  const int tid = threadIdx.x, w = tid>>6, lane = tid&63, col = lane&15, quad = lane>>4;
  const int m0 = blockIdx.y*128;       // n
  const int n0 = blockIdx.x*256;       // o
  const int b  = blockIdx.z;
  const int lr = lane>>2;
  const int gsw = ((lane&3) ^ (lr&3))*8;
  const u16* Ag = A + ((size_t)b*1024 + m0 + w*32 + lr)*512 + gsw;
  const u16* Bg = B + (size_t)(n0 + w*64 + lr)*512 + gsw;
  const int mw = (w&1)*64, nw = (w>>1)*128;
  const int fsw = (quad ^ (col&3))*8;

  v4f acc[4][8];
  #pragma unroll
  for (int i=0;i<4;++i)
    #pragma unroll
    for (int j=0;j<8;++j) acc[i][j] = v4zero();

  {
    u16* Ab = smem + (w*32)*32;
    u16* Bb = smem + 4096 + (w*64)*32;
    #pragma unroll
    for (int p = 0; p < 2; ++p) gl_lds16(Ag + (size_t)(p*16)*512, Ab + p*512);
    #pragma unroll
    for (int p = 0; p < 4; ++p) gl_lds16(Bg + (size_t)(p*16)*512, Bb + p*512);
  }

  for (int kt = 0; kt < 16; ++kt){
    __syncthreads();
    if (kt < 15){
      u16* Ab = smem + ((kt+1)&1)*12288 + (w*32)*32;
      u16* Bb = smem + ((kt+1)&1)*12288 + 4096 + (w*64)*32;
      int ko = (kt+1)*32;
      #pragma unroll
      for (int p = 0; p < 2; ++p) gl_lds16(Ag + (size_t)(p*16)*512 + ko, Ab + p*512);
      #pragma unroll
      for (int p = 0; p < 4; ++p) gl_lds16(Bg + (size_t)(p*16)*512 + ko, Bb + p*512);
    }
    const u16* As = smem + (kt&1)*12288;
    const u16* Bs = As + 4096;
    v8bf a[4], bb[8];
    #pragma unroll
    for (int i = 0; i < 4; ++i) a[i]  = *(const v8bf*)(As + (mw+i*16+col)*32 + fsw);
    #pragma unroll
    for (int j = 0; j < 8; ++j) bb[j] = *(const v8bf*)(Bs + (nw+j*16+col)*32 + fsw);
    #pragma unroll
    for (int i = 0; i < 4; ++i)
      #pragma unroll
      for (int j = 0; j < 8; ++j)
        acc[i][j] = MFMA16(a[i], bb[j], acc[i][j]);
  }
  __syncthreads();

  float bc[8];
  #pragma unroll
  for (int j = 0; j < 8; ++j)
    bc[j] = bias[n0 + nw + j*16 + col];

  if (n0 < 1024){
    u16* Cs = smem + w*(64*72);
    #pragma unroll
    for (int half = 0; half < 2; ++half){
      #pragma unroll
      for (int i = 0; i < 4; ++i)
        #pragma unroll
        for (int jj = 0; jj < 4; ++jj)
          #pragma unroll
          for (int r = 0; r < 4; ++r)
            Cs[(i*16+quad*4+r)*72 + jj*16+col] = f2bf(acc[i][half*4+jj][r] + bc[half*4+jj]);
      u16* dst = qk_t + (size_t)b*1024*1024;
      #pragma unroll
      for (int p = 0; p < 8; ++p){
        int rl = p*8 + (lane>>3), cl = (lane&7)*8;
        *(int4*)(dst + (size_t)(m0+mw+rl)*1024 + n0+nw+half*64+cl) = *(int4*)(Cs + rl*72 + cl);
      }
    }
  } else {
    u16* Ct = smem + w*(64*80);
    #pragma unroll
    for (int half = 0; half < 2; ++half){
      #pragma unroll
      for (int i = 0; i < 4; ++i)
        #pragma unroll
        for (int jj = 0; jj < 4; ++jj)
          #pragma unroll
          for (int r = 0; r < 4; ++r)
            Ct[(jj*16+col)*80 + i*16+quad*4+r] = f2bf(acc[i][half*4+jj][r] + bc[half*4+jj]);
      u16* dst = v_ws + (size_t)b*512*1024;
      #pragma unroll
      for (int p = 0; p < 8; ++p){
        int rl = p*8 + (lane>>3), cl = (lane&7)*8;
        *(int4*)(dst + (size_t)(n0-1024 + nw + half*64 + rl)*1024 + m0+mw+cl) = *(int4*)(Ct + rl*80 + cl);
      }
    }
  }
}

// ============ Generic bf16 GEMM (proj): dbuf BK=64, 1 barrier/iter ============
__global__ __launch_bounds__(256,2) void gemm_bt_kernel(
    const u16* __restrict__ A, long long sA,
    const u16* __restrict__ B, long long sB,
    u16* __restrict__ Cbf, float* __restrict__ Cf, long long sC,
    const float* __restrict__ bias_row,
    const float* __restrict__ bias_col,
    const float* __restrict__ residf, long long sR,
    int M, int N, int K)
{
  __shared__ u16 smem[32768];   // 65,536 B: 2 x (A 8192 + B 8192 u16)
  const int tid = threadIdx.x, w = tid>>6, lane = tid&63, col = lane&15, quad = lane>>4;
  const int m0 = blockIdx.y*128, n0 = blockIdx.x*128;
  const int lr8 = lane>>3;
  const int gsw = ((lane&7) ^ lr8)*8;
  const u16* Ag = A + (size_t)blockIdx.z*sA + (size_t)(m0 + w*32 + lr8)*K + gsw;
  const u16* Bg = B + (size_t)blockIdx.z*sB + (size_t)(n0 + w*32 + lr8)*K + gsw;
  const int mw = (w&1)*64, nw = (w>>1)*64;
  const int csw = col&7;
  const int nt = K >> 6;

  v4f acc[4][4];
  #pragma unroll
  for (int i=0;i<4;++i)
    #pragma unroll
    for (int j=0;j<4;++j) acc[i][j] = v4zero();

  {
    u16* Ab = smem + (w*32)*64;
    u16* Bb = smem + 8192 + (w*32)*64;
    #pragma unroll
    for (int p = 0; p < 4; ++p){
      gl_lds16(Ag + (size_t)(p*8)*K, Ab + p*512);
      gl_lds16(Bg + (size_t)(p*8)*K, Bb + p*512);
    }
  }

  for (int kt = 0; kt < nt; ++kt){
    __syncthreads();
    if (kt+1 < nt){
      u16* Ab = smem + ((kt+1)&1)*16384 + (w*32)*64;
      u16* Bb = smem + ((kt+1)&1)*16384 + 8192 + (w*32)*64;
      int ko = (kt+1)*64;
      #pragma unroll
      for (int p = 0; p < 4; ++p){
        gl_lds16(Ag + (size_t)(p*8)*K + ko, Ab + p*512);
        gl_lds16(Bg + (size_t)(p*8)*K + ko, Bb + p*512);
      }
    }
    const u16* As = smem + (kt&1)*16384;
    const u16* Bs = As + 8192;
    #pragma unroll
    for (int kh = 0; kh < 2; ++kh){
      const int fs = ((kh*4 + quad) ^ csw)*8;
      v8bf a[4], bb[4];
      #pragma unroll
      for (int i = 0; i < 4; ++i) a[i]  = *(const v8bf*)(As + (mw+i*16+col)*64 + fs);
      #pragma unroll
      for (int j = 0; j < 4; ++j) bb[j] = *(const v8bf*)(Bs + (nw+j*16+col)*64 + fs);
      #pragma unroll
      for (int i = 0; i < 4; ++i)
        #pragma unroll
        for (int j = 0; j < 4; ++j)
          acc[i][j] = MFMA16(a[i], bb[j], acc[i][j]);
    }
  }
  __syncthreads();

  float br[4][4], bc[4];
  #pragma unroll
  for (int i = 0; i < 4; ++i)
    #pragma unroll
    for (int r = 0; r < 4; ++r)
      br[i][r] = bias_row ? bias_row[m0+mw+i*16+quad*4+r] : 0.f;
  #pragma unroll
  for (int j = 0; j < 4; ++j)
    bc[j] = bias_col ? bias_col[n0+nw+j*16+col] : 0.f;

  if (Cf){
    float* Cb = Cf + (size_t)blockIdx.z*sC;
    const float* Rb = residf ? residf + (size_t)blockIdx.z*sR : nullptr;
    #pragma unroll
    for (int i = 0; i < 4; ++i)
      #pragma unroll
      for (int r = 0; r < 4; ++r){
        int row = m0+mw+i*16+quad*4+r;
        #pragma unroll
        for (int j = 0; j < 4; ++j){
          size_t goff = (size_t)row*N + n0+nw+j*16+col;
          float val = acc[i][j][r] + br[i][r] + bc[j];
          if (Rb) val += Rb[goff];
          Cb[goff] = val;
        }
      }
  } else {
    u16* Cs = smem + w*(64*72);
    #pragma unroll
    for (int i = 0; i < 4; ++i)
      #pragma unroll
      for (int j = 0; j < 4; ++j)
        #pragma unroll
        for (int r = 0; r < 4; ++r)
          Cs[(i*16+quad*4+r)*72 + j*16+col] = f2bf(acc[i][j][r] + br[i][r] + bc[j]);
    __syncthreads();
    u16* Cb = Cbf + (size_t)blockIdx.z*sC;
    #pragma unroll
    for (int p = 0; p < 8; ++p){
      int rl = p*8 + (lane>>3), cl = (lane&7)*8;
      size_t goff = (size_t)(m0+mw+rl)*N + n0+nw+cl;
      *(int4*)(Cb + goff) = *(int4*)(Cs + rl*72 + cl);
    }
  }
}

// ============ Fused flash attention: cross-tile pipeline (QK(t) || PV(t-1)), 80KB LDS ============
// qk[b][n][0..511]=q, [512..1023]=k; vv[b][c_all][m]; out[b][n][c_all]
// flat grid 512 x 256: qt=id>>6, bh=id&63. 2 blocks/CU (grid-limited), 2 waves/SIMD.
// The serial chain QK->exp->pack->PV left pipes idle (R1/R4: 46.5us, MfmaUtil 29%).
// Pipeline across tiles: PV(t-1) uses the CARRIED packed-P regs (ppA..ppD) + V(t-1),
// interleaved into QK(t)'s kk-loop -> 6 independent MFMA chains + exp/pack overlap the
// PV drain. V is TRI-buffered (V(t-1) must survive iter t); K stays double-buffered.
// LDS 80KB = 2 blocks/CU (same as grid limit -> free). Peeled iter0 + tail PV(15).
__global__ __launch_bounds__(256,2) void attn_kernel(const u16* __restrict__ qk, const u16* __restrict__ vv,
                                                     u16* __restrict__ outp){
  __shared__ u16 smem[40960];        // 80KB: Ks 2x[64][128] (32KB) + Vs 3x[128][64] (48KB)
  u16* Ks = smem;                    // 2 x 8192 u16
  u16* Vs = smem + 16384;            // 3 x 8192 u16
  const int id = blockIdx.x;
  const int qt = id >> 6, bh = id & 63, b = bh >> 2, h = bh & 3;
  const int n0 = qt*128;
  const int tid = threadIdx.x, w = tid>>6, lane = tid&63;
  const int nl = lane & 31, hi = lane >> 5;
  const int key = nl & 7;
  const size_t bq = (size_t)b*1024*1024;
  const float scale2 = 0.12751742f;  // (1/sqrt(128)) * log2(e)

  // Q as B-operand fragments in registers: col n = n0+w*32+nl, k granule kk*2+hi
  v8bf qf[8];
  {
    const u16* qbase = qk + bq + (size_t)(n0 + w*32 + nl)*1024 + h*128 + hi*8;
    #pragma unroll
    for (int kk = 0; kk < 8; ++kk)
      qf[kk] = *(const v8bf*)(qbase + kk*16);
  }

  v16f o[4];
  #pragma unroll
  for (int j=0;j<4;++j)
    #pragma unroll
    for (int r=0;r<16;++r) o[j][r] = 0.f;
  float lsum = 0.f;

  // staging lane constants (swizzle folded into global source granule)
  const int krow = w*4 + (lane>>4);
  const int kgr  = (lane&15) ^ (krow&7);
  const u16* kg_base = qk + bq + (size_t)krow*1024 + 512 + h*128 + kgr*8;
  const int vrow = w*8 + (lane>>3);
  const int vgr  = (lane&7) ^ (vrow&7);
  const u16* vg_base = vv + ((size_t)b*512 + h*128 + vrow)*1024 + vgr*8;

  // prologue: stage K(0)->Ks[0], V(0)->Vs[0]
  #pragma unroll
  for (int p = 0; p < 4; ++p)
    gl_lds16(kg_base + (size_t)(p*16)*1024, Ks + (w*4)*128 + p*2048);
  #pragma unroll
  for (int p = 0; p < 4; ++p)
    gl_lds16(vg_base + (size_t)(p*32)*1024, Vs + (w*8)*64 + p*2048);

  v8bf ppA, ppB, ppC, ppD;           // carried packed P fragments (tile t-1)
  const u16* Vprev = Vs;             // V buffer of tile t-1
  int vb = 0;                        // V buffer index of current tile

  // ---- iter 0 (peeled: QK+exp+pack only, no PV) ----
  __syncthreads();                   // tile 0 resident
  {
    // prefetch tile 1: K->Ks[1], V->Vs[1]
    u16* kl = Ks + (1<<13) + (w*4)*128;
    #pragma unroll
    for (int p = 0; p < 4; ++p)
      gl_lds16(kg_base + (size_t)(64 + p*16)*1024, kl + p*2048);
    u16* vl = Vs + (1<<13) + (w*8)*64;
    #pragma unroll
    for (int p = 0; p < 4; ++p)
      gl_lds16(vg_base + (size_t)(p*32)*1024 + 64, vl + p*2048);

    const u16* Kc = Ks;
    v16f s0, s1;
    #pragma unroll
    for (int r=0;r<16;++r){ s0[r]=0.f; s1[r]=0.f; }
    __builtin_amdgcn_s_setprio(1);
    #pragma unroll
    for (int kk = 0; kk < 8; ++kk){
      int g = (((kk*2 + hi) ^ key) << 3);
      v8bf k0 = *(const v8bf*)(Kc + (nl<<7) + g);
      v8bf k1 = *(const v8bf*)(Kc + ((32+nl)<<7) + g);
      s0 = MFMA32(k0, qf[kk], s0);
      s1 = MFMA32(k1, qf[kk], s1);
    }
    __builtin_amdgcn_s_setprio(0);
    #pragma unroll
    for (int r = 0; r < 16; ++r){
      s0[r] = __builtin_amdgcn_exp2f(s0[r]*scale2);
      s1[r] = __builtin_amdgcn_exp2f(s1[r]*scale2);
      lsum += s0[r] + s1[r];
    }
    PACK8(s0, 0, ppA); PACK8(s0, 8, ppB); PACK8(s1, 0, ppC); PACK8(s1, 8, ppD);
  }
  vb = 1;                            // tile 1 -> Vs[1]; Vprev stays Vs[0]

  // ---- main loop: QK(t) interleaved with PV(t-1) ----
  for (int t = 1; t < 16; ++t){
    __syncthreads();                 // tile t resident; V(t-1) intact (tri-buffer)
    int vbn = vb + 1; if (vbn == 3) vbn = 0;
    if (t < 15){
      int mt2 = t*64 + 64;
      u16* kl = Ks + (((t+1)&1)<<13) + (w*4)*128;
      #pragma unroll
      for (int p = 0; p < 4; ++p)
        gl_lds16(kg_base + (size_t)(mt2 + p*16)*1024, kl + p*2048);
      u16* vl = Vs + (vbn<<13) + (w*8)*64;
      #pragma unroll
      for (int p = 0; p < 4; ++p)
        gl_lds16(vg_base + (size_t)(p*32)*1024 + mt2, vl + p*2048);
    }

    const u16* Kc = Ks + ((t&1)<<13);
    v16f s0, s1;
    #pragma unroll
    for (int r=0;r<16;++r){ s0[r]=0.f; s1[r]=0.f; }
    __builtin_amdgcn_s_setprio(1);
    #pragma unroll
    for (int kk = 0; kk < 8; ++kk){
      int g = (((kk*2 + hi) ^ key) << 3);
      v8bf k0 = *(const v8bf*)(Kc + (nl<<7) + g);
      v8bf k1 = *(const v8bf*)(Kc + ((32+nl)<<7) + g);
      s0 = MFMA32(k0, qf[kk], s0);
      s1 = MFMA32(k1, qf[kk], s1);
      if (kk == 1){ PVBLK(0, ppA); }
      if (kk == 3){ PVBLK(1, ppB); }
      if (kk == 5){ PVBLK(2, ppC); }
      if (kk == 7){ PVBLK(3, ppD); }
    }
    __builtin_amdgcn_s_setprio(0);

    #pragma unroll
    for (int r = 0; r < 16; ++r){
      s0[r] = __builtin_amdgcn_exp2f(s0[r]*scale2);
      s1[r] = __builtin_amdgcn_exp2f(s1[r]*scale2);
      lsum += s0[r] + s1[r];
    }
    PACK8(s0, 0, ppA); PACK8(s0, 8, ppB); PACK8(s1, 0, ppC); PACK8(s1, 8, ppD);

    Vprev = Vs + (vb<<13);
    vb = vbn;
  }

  // ---- tail: PV(15) ----
  __builtin_amdgcn_s_setprio(1);
  PVBLK(0, ppA); PVBLK(1, ppB); PVBLK(2, ppC); PVBLK(3, ppD);
  __builtin_amdgcn_s_setprio(0);
  __syncthreads();

  // full row-sum for q-row nl (other half of m lives in lane^32), then redistribute
  // 1/l to the 32x32 C/D row layout: row(reg) = (reg&3) + 8*(reg>>2) + 4*hi
  lsum += __shfl_xor(lsum, 32);
  float invl[16];
  #pragma unroll
  for (int r = 0; r < 16; ++r){
    int nr = (r&3) + 8*(r>>2) + 4*hi;
    invl[r] = 1.f / __shfl(lsum, nr);
  }

  // bounce O through LDS (swizzled [128][128]) for coalesced 16B stores
  #pragma unroll
  for (int j = 0; j < 4; ++j)
    #pragma unroll
    for (int r = 0; r < 16; ++r){
      int rr = w*32 + (r&3) + 8*(r>>2) + 4*hi;
      int c  = j*32 + nl;
      smem[(rr<<7) + ((((c>>3) ^ (rr&7))<<3)) + (c&7)] = f2bf(o[j][r] * invl[r]);
    }
  __syncthreads();
  #pragma unroll
  for (int p = 0; p < 8; ++p){
    int nr = p*16 + (tid>>4);
    int gc = (tid&15) ^ (nr&7);
    *(int4*)(outp + ((size_t)b*1024 + n0 + nr)*512 + h*128 + ((tid&15)<<3)) =
      *(int4*)(smem + (nr<<7) + (gc<<3));
  }
}

extern "C" void kernel_launch(void* const* d_in, const int* in_sizes, int n_in,
                              void* d_out, int out_size, void* d_ws, size_t ws_size,
                              hipStream_t stream){
  const float* x      = (const float*)d_in[0];
  const float* norm_w = (const float*)d_in[1];
  const float* norm_b = (const float*)d_in[2];
  const float* qkv_w  = (const float*)d_in[3];
  const float* qkv_b  = (const float*)d_in[4];
  const float* proj_w = (const float*)d_in[5];
  const float* proj_b = (const float*)d_in[6];
  float* out = (float*)d_out;

  u16* h_t   = (u16*)d_ws;                                  // [16][1024][512]
  u16* qk_t  = h_t  + (size_t)16*1024*512;                  // [16][1024][1024]
  u16* v_ws  = qk_t + (size_t)16*1024*1024;                 // [16][512][1024]
  u16* wq_bf = v_ws + (size_t)16*512*1024;                  // [1536][512]
  u16* wp_bf = wq_bf + (size_t)1536*512;                    // [512][512]
  u16* attnout = h_t;                                       // reuse

  cvt2_kernel<<<1024, 256, 0, stream>>>(qkv_w, wq_bf, 1536*512, proj_w, wp_bf, 512*512);
  gn_fused_kernel<<<512, 256, 0, stream>>>(x, norm_w, norm_b, h_t);

  gemm_qkv_kernel<<<dim3(6,8,16), 256, 0, stream>>>(h_t, wq_bf, qkv_b, qk_t, v_ws);

  attn_kernel<<<512, 256, 0, stream>>>(qk_t, v_ws, attnout);

  gemm_bt_kernel<<<dim3(8,4,16), 256, 0, stream>>>(
      wp_bf, 0, attnout, (long long)1024*512,
      nullptr, out, (long long)512*1024, proj_b, nullptr, x, (long long)512*1024, 512, 1024, 512);
}

// Round 6
// 202.595 us; speedup vs baseline: 1.1610x; 1.0024x over previous
//
#include <hip/hip_runtime.h>

typedef __bf16 v8bf __attribute__((ext_vector_type(8)));
typedef float  v4f  __attribute__((ext_vector_type(4)));
typedef float  v16f __attribute__((ext_vector_type(16)));
typedef unsigned short u16;

__device__ __forceinline__ u16 f2bf(float f){
  __bf16 h = (__bf16)f;
  union { __bf16 h; u16 u; } c; c.h = h; return c.u;
}
__device__ __forceinline__ v4f v4zero(){ v4f z; z[0]=0.f; z[1]=0.f; z[2]=0.f; z[3]=0.f; return z; }

#define MFMA16(a,b,c) __builtin_amdgcn_mfma_f32_16x16x32_bf16((a),(b),(c),0,0,0)
#define MFMA32(a,b,c) __builtin_amdgcn_mfma_f32_32x32x16_bf16((a),(b),(c),0,0,0)

// async global->LDS, 16B per lane; LDS dest = wave-uniform base + lane*16
__device__ __forceinline__ void gl_lds16(const u16* g, u16* l){
  __builtin_amdgcn_global_load_lds((const __attribute__((address_space(1))) void*)g,
                                   (__attribute__((address_space(3))) void*)l, 16, 0, 0);
}

// v_cvt_pk_bf16_f32: pack two f32 -> one u32 of 2 bf16 (no builtin on gfx950)
__device__ __forceinline__ unsigned int pkbf(float lo, float hi){
  unsigned int r;
  asm("v_cvt_pk_bf16_f32 %0, %1, %2" : "=v"(r) : "v"(lo), "v"(hi));
  return r;
}

// ============ f32 -> bf16 bulk convert, both weight tensors in one launch ============
__global__ __launch_bounds__(256) void cvt2_kernel(const float* __restrict__ a, u16* __restrict__ da, int na,
                                                   const float* __restrict__ b, u16* __restrict__ db, int nb){
  int i = (blockIdx.x*256 + threadIdx.x)*4;
  const float* s; u16* d; int off;
  if (i < na){ s = a; d = da; off = i; }
  else { off = i - na; if (off >= nb) return; s = b; d = db; }
  float4 v = *(const float4*)(s + off);
  ushort4 o;
  o.x = f2bf(v.x); o.y = f2bf(v.y); o.z = f2bf(v.z); o.w = f2bf(v.w);
  *(ushort4*)(d + off) = o;
}

// ============ Fused GroupNorm: stats + apply + transpose in one kernel ============
__global__ __launch_bounds__(256) void gn_fused_kernel(const float* __restrict__ x, const float* __restrict__ nw,
                                                       const float* __restrict__ nb, u16* __restrict__ h_t){
  __shared__ float xs[16*1028 + 16];
  const int bg = blockIdx.x, b = bg >> 5, g = bg & 31, c0 = g*16;
  const int tid = threadIdx.x;
  const float* base = x + (size_t)(b*512 + c0)*1024;

  float s = 0.f, ss = 0.f;
  #pragma unroll
  for (int it = 0; it < 16; ++it){
    float4 v = *(const float4*)(base + it*1024 + tid*4);
    s  += v.x + v.y + v.z + v.w;
    ss += v.x*v.x + v.y*v.y + v.z*v.z + v.w*v.w;
    *(float4*)(xs + it*1028 + tid*4) = v;
  }
  #pragma unroll
  for (int off = 32; off > 0; off >>= 1){ s += __shfl_down(s, off); ss += __shfl_down(ss, off); }
  float* red = xs + 16*1028;
  int w = tid >> 6;
  if ((tid & 63) == 0){ red[w] = s; red[4+w] = ss; }
  __syncthreads();
  if (tid == 0){
    float S  = red[0]+red[1]+red[2]+red[3];
    float SS = red[4]+red[5]+red[6]+red[7];
    float mean = S * (1.f/16384.f);
    float var  = SS * (1.f/16384.f) - mean*mean;
    red[8] = mean;
    red[9] = rsqrtf(var + 1e-5f);
  }
  __syncthreads();
  const float mean = red[8], rstd = red[9];

  const int half = tid & 1, nbase = tid >> 1;
  float wv[8], bv[8];
  #pragma unroll
  for (int cl = 0; cl < 8; ++cl){
    int c = c0 + half*8 + cl;
    wv[cl] = nw[c] * rstd;
    bv[cl] = nb[c] - mean * wv[cl];
  }
  #pragma unroll
  for (int p = 0; p < 8; ++p){
    int n = nbase + p*128;
    alignas(16) u16 tmp[8];
    #pragma unroll
    for (int cl = 0; cl < 8; ++cl)
      tmp[cl] = f2bf(xs[(half*8 + cl)*1028 + n] * wv[cl] + bv[cl]);
    *(int4*)(h_t + ((size_t)b*1024 + n)*512 + c0 + half*8) = *(int4*)tmp;
  }
}

// ============ Fused QKV GEMM, double-buffered BK=32, 1 barrier/iter ============
__global__ __launch_bounds__(256,2) void gemm_qkv_kernel(
    const u16* __restrict__ A,       // h_t  [16][1024][512]
    const u16* __restrict__ B,       // wq_bf [1536][512]
    const float* __restrict__ bias,  // qkv_b [1536] f32
    u16* __restrict__ qk_t, u16* __restrict__ v_ws)
{
  __shared__ u16 smem[24576];    // 49,152 B: 2 x (A 4096 + B 8192 u16)
  const int tid = threadIdx.x, w = tid>>6, lane = tid&63, col = lane&15, quad = lane>>4;
  const int m0 = blockIdx.y*128;       // n
  const int n0 = blockIdx.x*256;       // o
  const int b  = blockIdx.z;
  const int lr = lane>>2;
  const int gsw = ((lane&3) ^ (lr&3))*8;
  const u16* Ag = A + ((size_t)b*1024 + m0 + w*32 + lr)*512 + gsw;
  const u16* Bg = B + (size_t)(n0 + w*64 + lr)*512 + gsw;
  const int mw = (w&1)*64, nw = (w>>1)*128;
  const int fsw = (quad ^ (col&3))*8;

  v4f acc[4][8];
  #pragma unroll
  for (int i=0;i<4;++i)
    #pragma unroll
    for (int j=0;j<8;++j) acc[i][j] = v4zero();

  {
    u16* Ab = smem + (w*32)*32;
    u16* Bb = smem + 4096 + (w*64)*32;
    #pragma unroll
    for (int p = 0; p < 2; ++p) gl_lds16(Ag + (size_t)(p*16)*512, Ab + p*512);
    #pragma unroll
    for (int p = 0; p < 4; ++p) gl_lds16(Bg + (size_t)(p*16)*512, Bb + p*512);
  }

  for (int kt = 0; kt < 16; ++kt){
    __syncthreads();
    if (kt < 15){
      u16* Ab = smem + ((kt+1)&1)*12288 + (w*32)*32;
      u16* Bb = smem + ((kt+1)&1)*12288 + 4096 + (w*64)*32;
      int ko = (kt+1)*32;
      #pragma unroll
      for (int p = 0; p < 2; ++p) gl_lds16(Ag + (size_t)(p*16)*512 + ko, Ab + p*512);
      #pragma unroll
      for (int p = 0; p < 4; ++p) gl_lds16(Bg + (size_t)(p*16)*512 + ko, Bb + p*512);
    }
    const u16* As = smem + (kt&1)*12288;
    const u16* Bs = As + 4096;
    v8bf a[4], bb[8];
    #pragma unroll
    for (int i = 0; i < 4; ++i) a[i]  = *(const v8bf*)(As + (mw+i*16+col)*32 + fsw);
    #pragma unroll
    for (int j = 0; j < 8; ++j) bb[j] = *(const v8bf*)(Bs + (nw+j*16+col)*32 + fsw);
    #pragma unroll
    for (int i = 0; i < 4; ++i)
      #pragma unroll
      for (int j = 0; j < 8; ++j)
        acc[i][j] = MFMA16(a[i], bb[j], acc[i][j]);
  }
  __syncthreads();

  float bc[8];
  #pragma unroll
  for (int j = 0; j < 8; ++j)
    bc[j] = bias[n0 + nw + j*16 + col];

  if (n0 < 1024){
    u16* Cs = smem + w*(64*72);
    #pragma unroll
    for (int half = 0; half < 2; ++half){
      #pragma unroll
      for (int i = 0; i < 4; ++i)
        #pragma unroll
        for (int jj = 0; jj < 4; ++jj)
          #pragma unroll
          for (int r = 0; r < 4; ++r)
            Cs[(i*16+quad*4+r)*72 + jj*16+col] = f2bf(acc[i][half*4+jj][r] + bc[half*4+jj]);
      u16* dst = qk_t + (size_t)b*1024*1024;
      #pragma unroll
      for (int p = 0; p < 8; ++p){
        int rl = p*8 + (lane>>3), cl = (lane&7)*8;
        *(int4*)(dst + (size_t)(m0+mw+rl)*1024 + n0+nw+half*64+cl) = *(int4*)(Cs + rl*72 + cl);
      }
    }
  } else {
    u16* Ct = smem + w*(64*80);
    #pragma unroll
    for (int half = 0; half < 2; ++half){
      #pragma unroll
      for (int i = 0; i < 4; ++i)
        #pragma unroll
        for (int jj = 0; jj < 4; ++jj)
          #pragma unroll
          for (int r = 0; r < 4; ++r)
            Ct[(jj*16+col)*80 + i*16+quad*4+r] = f2bf(acc[i][half*4+jj][r] + bc[half*4+jj]);
      u16* dst = v_ws + (size_t)b*512*1024;
      #pragma unroll
      for (int p = 0; p < 8; ++p){
        int rl = p*8 + (lane>>3), cl = (lane&7)*8;
        *(int4*)(dst + (size_t)(n0-1024 + nw + half*64 + rl)*1024 + m0+mw+cl) = *(int4*)(Ct + rl*80 + cl);
      }
    }
  }
}

// ============ Generic bf16 GEMM (proj): dbuf BK=64, 1 barrier/iter ============
__global__ __launch_bounds__(256,2) void gemm_bt_kernel(
    const u16* __restrict__ A, long long sA,
    const u16* __restrict__ B, long long sB,
    u16* __restrict__ Cbf, float* __restrict__ Cf, long long sC,
    const float* __restrict__ bias_row,
    const float* __restrict__ bias_col,
    const float* __restrict__ residf, long long sR,
    int M, int N, int K)
{
  __shared__ u16 smem[32768];   // 65,536 B: 2 x (A 8192 + B 8192 u16)
  const int tid = threadIdx.x, w = tid>>6, lane = tid&63, col = lane&15, quad = lane>>4;
  const int m0 = blockIdx.y*128, n0 = blockIdx.x*128;
  const int lr8 = lane>>3;
  const int gsw = ((lane&7) ^ lr8)*8;
  const u16* Ag = A + (size_t)blockIdx.z*sA + (size_t)(m0 + w*32 + lr8)*K + gsw;
  const u16* Bg = B + (size_t)blockIdx.z*sB + (size_t)(n0 + w*32 + lr8)*K + gsw;
  const int mw = (w&1)*64, nw = (w>>1)*64;
  const int csw = col&7;
  const int nt = K >> 6;

  v4f acc[4][4];
  #pragma unroll
  for (int i=0;i<4;++i)
    #pragma unroll
    for (int j=0;j<4;++j) acc[i][j] = v4zero();

  {
    u16* Ab = smem + (w*32)*64;
    u16* Bb = smem + 8192 + (w*32)*64;
    #pragma unroll
    for (int p = 0; p < 4; ++p){
      gl_lds16(Ag + (size_t)(p*8)*K, Ab + p*512);
      gl_lds16(Bg + (size_t)(p*8)*K, Bb + p*512);
    }
  }

  for (int kt = 0; kt < nt; ++kt){
    __syncthreads();
    if (kt+1 < nt){
      u16* Ab = smem + ((kt+1)&1)*16384 + (w*32)*64;
      u16* Bb = smem + ((kt+1)&1)*16384 + 8192 + (w*32)*64;
      int ko = (kt+1)*64;
      #pragma unroll
      for (int p = 0; p < 4; ++p){
        gl_lds16(Ag + (size_t)(p*8)*K + ko, Ab + p*512);
        gl_lds16(Bg + (size_t)(p*8)*K + ko, Bb + p*512);
      }
    }
    const u16* As = smem + (kt&1)*16384;
    const u16* Bs = As + 8192;
    #pragma unroll
    for (int kh = 0; kh < 2; ++kh){
      const int fs = ((kh*4 + quad) ^ csw)*8;
      v8bf a[4], bb[4];
      #pragma unroll
      for (int i = 0; i < 4; ++i) a[i]  = *(const v8bf*)(As + (mw+i*16+col)*64 + fs);
      #pragma unroll
      for (int j = 0; j < 4; ++j) bb[j] = *(const v8bf*)(Bs + (nw+j*16+col)*64 + fs);
      #pragma unroll
      for (int i = 0; i < 4; ++i)
        #pragma unroll
        for (int j = 0; j < 4; ++j)
          acc[i][j] = MFMA16(a[i], bb[j], acc[i][j]);
    }
  }
  __syncthreads();

  float br[4][4], bc[4];
  #pragma unroll
  for (int i = 0; i < 4; ++i)
    #pragma unroll
    for (int r = 0; r < 4; ++r)
      br[i][r] = bias_row ? bias_row[m0+mw+i*16+quad*4+r] : 0.f;
  #pragma unroll
  for (int j = 0; j < 4; ++j)
    bc[j] = bias_col ? bias_col[n0+nw+j*16+col] : 0.f;

  if (Cf){
    float* Cb = Cf + (size_t)blockIdx.z*sC;
    const float* Rb = residf ? residf + (size_t)blockIdx.z*sR : nullptr;
    #pragma unroll
    for (int i = 0; i < 4; ++i)
      #pragma unroll
      for (int r = 0; r < 4; ++r){
        int row = m0+mw+i*16+quad*4+r;
        #pragma unroll
        for (int j = 0; j < 4; ++j){
          size_t goff = (size_t)row*N + n0+nw+j*16+col;
          float val = acc[i][j][r] + br[i][r] + bc[j];
          if (Rb) val += Rb[goff];
          Cb[goff] = val;
        }
      }
  } else {
    u16* Cs = smem + w*(64*72);
    #pragma unroll
    for (int i = 0; i < 4; ++i)
      #pragma unroll
      for (int j = 0; j < 4; ++j)
        #pragma unroll
        for (int r = 0; r < 4; ++r)
          Cs[(i*16+quad*4+r)*72 + j*16+col] = f2bf(acc[i][j][r] + br[i][r] + bc[j]);
    __syncthreads();
    u16* Cb = Cbf + (size_t)blockIdx.z*sC;
    #pragma unroll
    for (int p = 0; p < 8; ++p){
      int rl = p*8 + (lane>>3), cl = (lane&7)*8;
      size_t goff = (size_t)(m0+mw+rl)*N + n0+nw+cl;
      *(int4*)(Cb + goff) = *(int4*)(Cs + rl*72 + cl);
    }
  }
}

// ============ Fused flash attention: counted-vmcnt pipeline (T4), K dbuf + V tri-buf ============
// qk[b][n][0..511]=q, [512..1023]=k; vv[b][c_all][m]; out[b][n][c_all]
// flat grid 512 x 256: qt=id>>6, bh=id&63. 2 blocks/CU (grid-limited).
// R1/R4 plateau (46.4us) theory: __syncthreads drains vmcnt(0) every iter, exposing
// HBM/L2 latency of the depth-1 prefetch. Fix: raw s_barrier + s_waitcnt vmcnt(4) --
// V(t+1) loads stay IN FLIGHT across the barrier. K double-buffered, issued depth-1
// (1 phase cover); V TRI-buffered, issued depth-2 (2 phases ~2k cyc cover HBM ~900cy).
// FIFO bookkeeping (per wave, order pinned by sched_barrier(0)): each iter issues
// [K(t+1) x4, V(t+2) x4]; at barrier t "all but newest 4" == K(t),V(t) done, V(t+1)
// flying -> vmcnt(4); t==15 -> vmcnt(0). In-register softmax (T12) unchanged.
__global__ __launch_bounds__(256,2) void attn_kernel(const u16* __restrict__ qk, const u16* __restrict__ vv,
                                                     u16* __restrict__ outp){
  __shared__ u16 smem[40960];        // 80KB: Ks 2x[64][128] (32KB) + Vs 3x[128][64] (48KB)
  u16* Ks = smem;                    // 2 x 8192 u16
  u16* Vs = smem + 16384;            // 3 x 8192 u16
  const int id = blockIdx.x;
  const int qt = id >> 6, bh = id & 63, b = bh >> 2, h = bh & 3;
  const int n0 = qt*128;
  const int tid = threadIdx.x, w = tid>>6, lane = tid&63;
  const int nl = lane & 31, hi = lane >> 5;
  const int key = nl & 7;
  const size_t bq = (size_t)b*1024*1024;
  const float scale2 = 0.12751742f;  // (1/sqrt(128)) * log2(e)

  // Q as B-operand fragments in registers: col n = n0+w*32+nl, k granule kk*2+hi
  v8bf qf[8];
  {
    const u16* qbase = qk + bq + (size_t)(n0 + w*32 + nl)*1024 + h*128 + hi*8;
    #pragma unroll
    for (int kk = 0; kk < 8; ++kk)
      qf[kk] = *(const v8bf*)(qbase + kk*16);
  }
  __builtin_amdgcn_sched_barrier(0);   // pin Q loads before the staging FIFO

  v16f o[4];
  #pragma unroll
  for (int j=0;j<4;++j)
    #pragma unroll
    for (int r=0;r<16;++r) o[j][r] = 0.f;
  float ls0 = 0.f, ls1 = 0.f, ls2 = 0.f, ls3 = 0.f;  // 4 independent sum chains

  // staging lane constants (swizzle folded into global source granule)
  const int krow = w*4 + (lane>>4);
  const int kgr  = (lane&15) ^ (krow&7);
  const u16* kg_base = qk + bq + (size_t)krow*1024 + 512 + h*128 + kgr*8;
  const int vrow = w*8 + (lane>>3);
  const int vgr  = (lane&7) ^ (vrow&7);
  const u16* vg_base = vv + ((size_t)b*512 + h*128 + vrow)*1024 + vgr*8;

  // prologue FIFO (order pinned): K(0)->Ks[0] | V(0)->Vs[0] | V(1)->Vs[1]
  #pragma unroll
  for (int p = 0; p < 4; ++p)
    gl_lds16(kg_base + (size_t)(p*16)*1024, Ks + (w*4)*128 + p*2048);
  __builtin_amdgcn_sched_barrier(0);
  #pragma unroll
  for (int p = 0; p < 4; ++p)
    gl_lds16(vg_base + (size_t)(p*32)*1024, Vs + (w*8)*64 + p*2048);
  __builtin_amdgcn_sched_barrier(0);
  #pragma unroll
  for (int p = 0; p < 4; ++p)
    gl_lds16(vg_base + (size_t)(p*32)*1024 + 64, Vs + 8192 + (w*8)*64 + p*2048);
  __builtin_amdgcn_sched_barrier(0);

  int vb = 0, vb2 = 2;                 // V read buf (t%3), V issue buf ((t+2)%3)
  for (int t = 0; t < 16; ++t){
    // counted-vmcnt barrier: certify K(t),V(t); keep V(t+1) in flight
    if (t < 15) asm volatile("s_waitcnt vmcnt(4)" ::: "memory");
    else        asm volatile("s_waitcnt vmcnt(0)" ::: "memory");
    __builtin_amdgcn_sched_barrier(0);
    __builtin_amdgcn_s_barrier();
    __builtin_amdgcn_sched_barrier(0);

    if (t < 15){                       // issue K(t+1) -> Ks[(t+1)&1]  (depth-1)
      u16* kl = Ks + (((t+1)&1)<<13) + (w*4)*128;
      int mt2 = t*64 + 64;
      #pragma unroll
      for (int p = 0; p < 4; ++p)
        gl_lds16(kg_base + (size_t)(mt2 + p*16)*1024, kl + p*2048);
    }
    __builtin_amdgcn_sched_barrier(0); // pin K-issue before V-issue (FIFO accounting)
    if (t < 14){                       // issue V(t+2) -> Vs[vb2]  (depth-2)
      u16* vl = Vs + (vb2<<13) + (w*8)*64;
      int mt3 = t*64 + 128;
      #pragma unroll
      for (int p = 0; p < 4; ++p)
        gl_lds16(vg_base + (size_t)(p*32)*1024 + mt3, vl + p*2048);
    }
    __builtin_amdgcn_sched_barrier(0);

    // S^T = K Q^T (raw): s0 covers m = mt+0..31, s1 covers m = mt+32..63; col = q-row nl
    const u16* Kc = Ks + ((t&1)<<13);
    v16f s0, s1;
    #pragma unroll
    for (int r=0;r<16;++r){ s0[r]=0.f; s1[r]=0.f; }
    __builtin_amdgcn_s_setprio(1);
    #pragma unroll
    for (int kk = 0; kk < 8; ++kk){
      int g = (((kk*2 + hi) ^ key) << 3);
      v8bf k0 = *(const v8bf*)(Kc + (nl<<7) + g);
      v8bf k1 = *(const v8bf*)(Kc + ((32+nl)<<7) + g);
      s0 = MFMA32(k0, qf[kk], s0);
      s1 = MFMA32(k1, qf[kk], s1);
    }
    __builtin_amdgcn_s_setprio(0);

    // p = exp2(s*scale2) in place; 4 independent lane-local sum chains
    #pragma unroll
    for (int r = 0; r < 16; r += 2){
      s0[r]   = __builtin_amdgcn_exp2f(s0[r]*scale2);
      s0[r+1] = __builtin_amdgcn_exp2f(s0[r+1]*scale2);
      s1[r]   = __builtin_amdgcn_exp2f(s1[r]*scale2);
      s1[r+1] = __builtin_amdgcn_exp2f(s1[r+1]*scale2);
      ls0 += s0[r]; ls1 += s0[r+1];
      ls2 += s1[r]; ls3 += s1[r+1];
    }

    // O += P V^T, P packed to A-frags in-register (cvt_pk + permlane32_swap)
    const u16* Vc = Vs + (vb<<13);
    #pragma unroll
    for (int half = 0; half < 2; ++half){
      const v16f& ps = half ? s1 : s0;
      #pragma unroll
      for (int sel = 0; sel < 2; ++sel){
        const int sb = sel*8;
        unsigned int pA = pkbf(ps[sb+0], ps[sb+1]);
        unsigned int pB = pkbf(ps[sb+2], ps[sb+3]);
        unsigned int pC = pkbf(ps[sb+4], ps[sb+5]);
        unsigned int pD = pkbf(ps[sb+6], ps[sb+7]);
        asm("v_permlane32_swap_b32 %0, %1" : "+v"(pA), "+v"(pC));
        asm("v_permlane32_swap_b32 %0, %1" : "+v"(pB), "+v"(pD));
        union { v8bf v; unsigned int u[4]; } pa;
        pa.u[0] = pA; pa.u[1] = pB; pa.u[2] = pC; pa.u[3] = pD;
        const int kkv = half*2 + sel;
        const int gv = (((kkv*2 + hi) ^ key) << 3);
        __builtin_amdgcn_s_setprio(1);
        #pragma unroll
        for (int j = 0; j < 4; ++j){
          v8bf bv = *(const v8bf*)(Vc + ((j*32 + nl)<<6) + gv);
          o[j] = MFMA32(pa.v, bv, o[j]);
        }
        __builtin_amdgcn_s_setprio(0);
      }
    }

    vb  = (vb  == 2) ? 0 : vb  + 1;
    vb2 = (vb2 == 2) ? 0 : vb2 + 1;
  }
  __syncthreads();

  // full row-sum for q-row nl (other half of m lives in lane^32), then redistribute
  // 1/l to the 32x32 C/D row layout: row(reg) = (reg&3) + 8*(reg>>2) + 4*hi
  float lsum = (ls0 + ls1) + (ls2 + ls3);
  lsum += __shfl_xor(lsum, 32);
  float invl[16];
  #pragma unroll
  for (int r = 0; r < 16; ++r){
    int nr = (r&3) + 8*(r>>2) + 4*hi;
    invl[r] = 1.f / __shfl(lsum, nr);
  }

  // bounce O through LDS (swizzled [128][128]) for coalesced 16B stores
  #pragma unroll
  for (int j = 0; j < 4; ++j)
    #pragma unroll
    for (int r = 0; r < 16; ++r){
      int rr = w*32 + (r&3) + 8*(r>>2) + 4*hi;
      int c  = j*32 + nl;
      smem[(rr<<7) + ((((c>>3) ^ (rr&7))<<3)) + (c&7)] = f2bf(o[j][r] * invl[r]);
    }
  __syncthreads();
  #pragma unroll
  for (int p = 0; p < 8; ++p){
    int nr = p*16 + (tid>>4);
    int gc = (tid&15) ^ (nr&7);
    *(int4*)(outp + ((size_t)b*1024 + n0 + nr)*512 + h*128 + ((tid&15)<<3)) =
      *(int4*)(smem + (nr<<7) + (gc<<3));
  }
}

extern "C" void kernel_launch(void* const* d_in, const int* in_sizes, int n_in,
                              void* d_out, int out_size, void* d_ws, size_t ws_size,
                              hipStream_t stream){
  const float* x      = (const float*)d_in[0];
  const float* norm_w = (const float*)d_in[1];
  const float* norm_b = (const float*)d_in[2];
  const float* qkv_w  = (const float*)d_in[3];
  const float* qkv_b  = (const float*)d_in[4];
  const float* proj_w = (const float*)d_in[5];
  const float* proj_b = (const float*)d_in[6];
  float* out = (float*)d_out;

  u16* h_t   = (u16*)d_ws;                                  // [16][1024][512]
  u16* qk_t  = h_t  + (size_t)16*1024*512;                  // [16][1024][1024]
  u16* v_ws  = qk_t + (size_t)16*1024*1024;                 // [16][512][1024]
  u16* wq_bf = v_ws + (size_t)16*512*1024;                  // [1536][512]
  u16* wp_bf = wq_bf + (size_t)1536*512;                    // [512][512]
  u16* attnout = h_t;                                       // reuse

  cvt2_kernel<<<1024, 256, 0, stream>>>(qkv_w, wq_bf, 1536*512, proj_w, wp_bf, 512*512);
  gn_fused_kernel<<<512, 256, 0, stream>>>(x, norm_w, norm_b, h_t);

  gemm_qkv_kernel<<<dim3(6,8,16), 256, 0, stream>>>(h_t, wq_bf, qkv_b, qk_t, v_ws);

  attn_kernel<<<512, 256, 0, stream>>>(qk_t, v_ws, attnout);

  gemm_bt_kernel<<<dim3(8,4,16), 256, 0, stream>>>(
      wp_bf, 0, attnout, (long long)1024*512,
      nullptr, out, (long long)512*1024, proj_b, nullptr, x, (long long)512*1024, 512, 1024, 512);
}